// Round 12
// baseline (1140.423 us; speedup 1.0000x reference)
//
#include <hip/hip_runtime.h>
#include <stdint.h>

#define B_ 2
#define T_ 2048
#define C_ 256
#define H_ 4
#define L_ 4
#define FF 1024
#define V_ 32000

typedef short bfrag __attribute__((ext_vector_type(8)));   // 8 x bf16 (MFMA A/B operand)
typedef float facc  __attribute__((ext_vector_type(4)));   // MFMA C/D
typedef short s4v   __attribute__((ext_vector_type(4)));
typedef short s8v   __attribute__((ext_vector_type(8)));
typedef unsigned short u16;

#define FLAG_BIAS 1
#define FLAG_RELU 4
#define FLAG_BF16 8
#define FLAG_NT   16

__device__ __forceinline__ u16 f2bf(float f) {
  uint32_t x = __float_as_uint(f);
  return (u16)((x + 0x7fffu + ((x >> 16) & 1u)) >> 16);
}
__device__ __forceinline__ float bf2f(u16 u) {
  return __uint_as_float(((uint32_t)u) << 16);
}

__device__ __forceinline__ void gload_lds16(const void* g, void* l) {
  __builtin_amdgcn_global_load_lds(
      (const __attribute__((address_space(1))) uint32_t*)g,
      (__attribute__((address_space(3))) uint32_t*)l, 16, 0, 0);
}

// ---------------------------------------------------------------- all weight transposes
__global__ __launch_bounds__(256) void transpose_all(
    const float* __restrict__ wq, const float* __restrict__ wk,
    const float* __restrict__ wv, const float* __restrict__ wo,
    const float* __restrict__ w1, const float* __restrict__ w2,
    const float* __restrict__ wf,
    u16* __restrict__ wqkvT, u16* __restrict__ woT, u16* __restrict__ w1T,
    u16* __restrict__ w2T, u16* __restrict__ wfT) {
  int bid = blockIdx.x;
  const float* in;
  u16* out;
  int R, Cc, cx, ry;
  long long zi, zo;
  if (bid < 3072) {              // wq/wk/wv: [16][256][256] -> wqkvT [L][3][1024][256]
    int job = bid >> 10, w = bid & 1023;
    int z = w >> 6, t = w & 63;
    cx = t & 7; ry = t >> 3; R = 256; Cc = 256;
    in = (job == 0 ? wq : job == 1 ? wk : wv);
    zi = (long long)z * 65536;
    zo = (long long)(z >> 2) * 786432 + (long long)(z & 3) * 65536
       + (long long)job * 262144;
    out = wqkvT;
  } else if (bid < 4096) {       // wo: [4][1024][256] -> [4][256][1024]
    int w = bid - 3072; int z = w >> 8, t = w & 255;
    cx = t & 7; ry = t >> 3; R = 1024; Cc = 256;
    in = wo; zi = (long long)z * 262144; zo = zi; out = woT;
  } else if (bid < 5120) {       // w1: [4][256][1024] -> [4][1024][256]
    int w = bid - 4096; int z = w >> 8, t = w & 255;
    cx = t & 31; ry = t >> 5; R = 256; Cc = 1024;
    in = w1; zi = (long long)z * 262144; zo = zi; out = w1T;
  } else if (bid < 6144) {       // w2: [4][1024][256] -> [4][256][1024]
    int w = bid - 5120; int z = w >> 8, t = w & 255;
    cx = t & 7; ry = t >> 3; R = 1024; Cc = 256;
    in = w2; zi = (long long)z * 262144; zo = zi; out = w2T;
  } else {                       // wf: [256][32000] -> [32000][256]
    int t = bid - 6144; cx = t % 1000; ry = t / 1000;
    R = 256; Cc = 32000; in = wf; zi = 0; zo = 0; out = wfT;
  }
  __shared__ float tile[32][33];
  int c0 = cx * 32, r0 = ry * 32;
  int tx = threadIdx.x & 31, ty = threadIdx.x >> 5;
#pragma unroll
  for (int i = ty; i < 32; i += 8)
    tile[i][tx] = in[zi + (long long)(r0 + i) * Cc + (c0 + tx)];
  __syncthreads();
#pragma unroll
  for (int i = ty; i < 32; i += 8)
    out[zo + (long long)(c0 + i) * R + (r0 + tx)] = f2bf(tile[tx][i]);
}

// ---------------------------------------------------------------- V transpose (u16)
__global__ __launch_bounds__(256) void transpose_v(const u16* __restrict__ qkv,
                                                   u16* __restrict__ vt) {
  __shared__ u16 tile[32][33];
  int z = blockIdx.z, b = z >> 2, h = z & 3;
  const u16* in = qkv + (long long)b * T_ * 3072 + 2048 + h * 256;
  int t0 = blockIdx.x * 32, d0 = blockIdx.y * 32;
  int tx = threadIdx.x & 31, ty = threadIdx.x >> 5;
#pragma unroll
  for (int i = ty; i < 32; i += 8)
    tile[i][tx] = in[(long long)(t0 + i) * 3072 + (d0 + tx)];
  __syncthreads();
#pragma unroll
  for (int i = ty; i < 32; i += 8)
    vt[((long long)z * 256 + d0 + i) * T_ + (t0 + tx)] = tile[tx][i];
}

// ---------------------------------------------------------------- embed + LN1(l=0) fused
__global__ __launch_bounds__(256) void embed_ln(const int* __restrict__ tok,
                                                const float* __restrict__ emb,
                                                const float* __restrict__ pos,
                                                u16* __restrict__ xn,
                                                const float* __restrict__ g,
                                                const float* __restrict__ b) {
  int wid = threadIdx.x >> 6, lane = threadIdx.x & 63;
  int row = blockIdx.x * 4 + wid;
  int t = row & (T_ - 1);
  float4 ev = ((const float4*)(emb + (long long)tok[row] * C_))[lane];
  float4 pv = ((const float4*)(pos + (long long)t * C_))[lane];
  float4 v;
  v.x = ev.x + pv.x; v.y = ev.y + pv.y; v.z = ev.z + pv.z; v.w = ev.w + pv.w;
  float s = v.x + v.y + v.z + v.w;
#pragma unroll
  for (int o = 32; o > 0; o >>= 1) s += __shfl_xor(s, o);
  float mean = s * (1.f / 256.f);
  float d0 = v.x - mean, d1 = v.y - mean, d2 = v.z - mean, d3 = v.w - mean;
  float q2 = d0 * d0 + d1 * d1 + d2 * d2 + d3 * d3;
#pragma unroll
  for (int o = 32; o > 0; o >>= 1) q2 += __shfl_xor(q2, o);
  float rstd = rsqrtf(q2 * (1.f / 256.f) + 1e-5f);
  float4 gv = ((const float4*)g)[lane];
  float4 bv = ((const float4*)b)[lane];
  u16 tmp[4] = {f2bf(d0 * rstd * gv.x + bv.x), f2bf(d1 * rstd * gv.y + bv.y),
                f2bf(d2 * rstd * gv.z + bv.z), f2bf(d3 * rstd * gv.w + bv.w)};
  *(s4v*)&xn[(long long)row * C_ + lane * 4] = *(const s4v*)tmp;
}

// ---------------------------------------------------------------- split-K reduce (bf16 partials) + bias + residual + LN
__global__ __launch_bounds__(256) void reduce_ln(const u16* __restrict__ pbuf,
                                                 u16* __restrict__ xn,
                                                 const float* __restrict__ bias,
                                                 const float* __restrict__ g,
                                                 const float* __restrict__ b) {
  int wid = threadIdx.x >> 6, lane = threadIdx.x & 63;
  long long row = (long long)blockIdx.x * 4 + wid;
  const u16* p = pbuf + row * C_ + lane * 4;
  const int SL = 1048576;
  s4v rv = *(const s4v*)&xn[row * C_ + lane * 4];
  float4 bi = ((const float4*)bias)[lane];
  float4 v;
  v.x = bf2f((u16)rv[0]) + bi.x;
  v.y = bf2f((u16)rv[1]) + bi.y;
  v.z = bf2f((u16)rv[2]) + bi.z;
  v.w = bf2f((u16)rv[3]) + bi.w;
#pragma unroll
  for (int sI = 0; sI < 4; ++sI) {
    s4v pv = *(const s4v*)(p + sI * SL);
    v.x += bf2f((u16)pv[0]);
    v.y += bf2f((u16)pv[1]);
    v.z += bf2f((u16)pv[2]);
    v.w += bf2f((u16)pv[3]);
  }
  float s = v.x + v.y + v.z + v.w;
#pragma unroll
  for (int o = 32; o > 0; o >>= 1) s += __shfl_xor(s, o);
  float mean = s * (1.f / 256.f);
  float d0 = v.x - mean, d1 = v.y - mean, d2 = v.z - mean, d3 = v.w - mean;
  float q2 = d0 * d0 + d1 * d1 + d2 * d2 + d3 * d3;
#pragma unroll
  for (int o = 32; o > 0; o >>= 1) q2 += __shfl_xor(q2, o);
  float rstd = rsqrtf(q2 * (1.f / 256.f) + 1e-5f);
  float4 gv = ((const float4*)g)[lane];
  float4 bv = ((const float4*)b)[lane];
  u16 tmp[4] = {f2bf(d0 * rstd * gv.x + bv.x), f2bf(d1 * rstd * gv.y + bv.y),
                f2bf(d2 * rstd * gv.z + bv.z), f2bf(d3 * rstd * gv.w + bv.w)};
  *(s4v*)&xn[row * C_ + lane * 4] = *(const s4v*)tmp;
}

// ---------------------------------------------------------------- flash attention
// 2 waves x 32 q-rows (2 m-frags each): K/V LDS fragments reused across both
// m-MFMAs -> LDS reads per FLOP halved. wave0 -> lo 32-tile, wave1 -> hi tile
// (causal-balanced pairing). Same layouts/swizzles/staging as before.
__global__ __launch_bounds__(128, 1) void flash_k(const u16* __restrict__ qkv,
                                                  const u16* __restrict__ vt,
                                                  u16* __restrict__ ocat) {
  __shared__ u16 Klds[2][64 * 256];    // 2 x 32 KB
  __shared__ u16 Vlds[2][256 * 64];    // 2 x 32 KB
  __shared__ u16 Plds[2][2048];        // per-wave P, 32x64
  int ib = blockIdx.x, z = blockIdx.y;
  int b = z >> 2, h = z & 3;
  int tid = threadIdx.x, lane = tid & 63, wid = tid >> 6;  // wid 0/1
  int l15 = lane & 15, lg = lane >> 4;
  int wrow0 = (wid == 0) ? (ib * 32) : (2016 - ib * 32);
  int jmax = (2016 - ib * 32 + 31) >> 6;

  bfrag qf[2][8];
#pragma unroll
  for (int m = 0; m < 2; ++m) {
    const u16* qrow = qkv + (long long)(b * T_ + wrow0 + m * 16 + l15) * 3072
                    + h * 256 + lg * 8;
#pragma unroll
    for (int ks = 0; ks < 8; ++ks) qf[m][ks] = *(const bfrag*)(qrow + ks * 32);
  }
  facc zf = {0.f, 0.f, 0.f, 0.f};
  facc O[2][16];
#pragma unroll
  for (int m = 0; m < 2; ++m)
#pragma unroll
    for (int nb = 0; nb < 16; ++nb) O[m][nb] = zf;
  float mrow[2][4], lrow[2][4];
#pragma unroll
  for (int m = 0; m < 2; ++m)
#pragma unroll
    for (int i = 0; i < 4; ++i) { mrow[m][i] = -1e30f; lrow[m][i] = 0.f; }

  const u16* kgbase = qkv + (long long)(b * T_) * 3072 + 1024 + h * 256;
  const u16* vgbase = vt + (long long)z * 256 * 2048;

  auto stage = [&](int j) {
    int kv0 = j * 64;
    int bufi = j & 1;
#pragma unroll
    for (int c = 0; c < 16; ++c) {
      int chunk = wid * 16 + c;
      int krow = chunk * 2 + (lane >> 5);
      int kcb = ((lane & 31) * 16) ^ ((krow & 7) << 4);
      gload_lds16(kgbase + (long long)(kv0 + krow) * 3072 + (kcb >> 1),
                  &Klds[bufi][chunk * 512 + lane * 8]);
      int drow = chunk * 8 + (lane >> 3);
      int vcb = ((lane & 7) * 16) ^ ((drow & 7) << 4);
      gload_lds16(vgbase + (long long)drow * 2048 + kv0 + (vcb >> 1),
                  &Vlds[bufi][chunk * 512 + lane * 8]);
    }
  };

  stage(0);
  for (int j = 0; j <= jmax; ++j) {
    __syncthreads();
    if (j < jmax) stage(j + 1);
    const u16* Kb = Klds[j & 1];
    const u16* Vb = Vlds[j & 1];
    int kv0 = j * 64;
    bool skip = (kv0 > wrow0 + 31);
    if (!skip) {
      bool full = (kv0 + 63 <= wrow0);
      facc s[2][4];
#pragma unroll
      for (int m = 0; m < 2; ++m)
#pragma unroll
        for (int nb = 0; nb < 4; ++nb) s[m][nb] = zf;
      // QK^T: K fragment read once per (nb,ks), reused across both m
#pragma unroll
      for (int nb = 0; nb < 4; ++nb) {
#pragma unroll
        for (int ks = 0; ks < 8; ++ks) {
          int row = nb * 16 + l15;
          bfrag kb = *(const bfrag*)&Kb[row * 256 +
              (((ks * 64 + lg * 16) ^ ((row & 7) << 4)) >> 1)];
#pragma unroll
          for (int m = 0; m < 2; ++m)
            s[m][nb] = __builtin_amdgcn_mfma_f32_16x16x32_bf16(qf[m][ks], kb, s[m][nb], 0, 0, 0);
        }
      }
#pragma unroll
      for (int m = 0; m < 2; ++m) {
        float pmax[4] = {-1e30f, -1e30f, -1e30f, -1e30f};
#pragma unroll
        for (int nb = 0; nb < 4; ++nb) {
          int col = kv0 + nb * 16 + l15;
#pragma unroll
          for (int i = 0; i < 4; ++i) {
            float vsc = s[m][nb][i] * 0.0625f;
            int rowa = wrow0 + m * 16 + lg * 4 + i;
            if (!full && col > rowa) vsc = -1e30f;
            s[m][nb][i] = vsc;
            pmax[i] = fmaxf(pmax[i], vsc);
          }
        }
#pragma unroll
        for (int i = 0; i < 4; ++i) {
          pmax[i] = fmaxf(pmax[i], __shfl_xor(pmax[i], 1));
          pmax[i] = fmaxf(pmax[i], __shfl_xor(pmax[i], 2));
          pmax[i] = fmaxf(pmax[i], __shfl_xor(pmax[i], 4));
          pmax[i] = fmaxf(pmax[i], __shfl_xor(pmax[i], 8));
        }
        float corr[4], rsum[4];
#pragma unroll
        for (int i = 0; i < 4; ++i) {
          float mn = fmaxf(mrow[m][i], pmax[i]);
          corr[i] = __expf(mrow[m][i] - mn);
          mrow[m][i] = mn;
          rsum[i] = 0.f;
        }
#pragma unroll
        for (int nb = 0; nb < 4; ++nb)
#pragma unroll
          for (int i = 0; i < 4; ++i) {
            float p = __expf(s[m][nb][i] - mrow[m][i]);
            s[m][nb][i] = p;
            rsum[i] += p;
          }
#pragma unroll
        for (int i = 0; i < 4; ++i) {
          rsum[i] += __shfl_xor(rsum[i], 1);
          rsum[i] += __shfl_xor(rsum[i], 2);
          rsum[i] += __shfl_xor(rsum[i], 4);
          rsum[i] += __shfl_xor(rsum[i], 8);
          lrow[m][i] = lrow[m][i] * corr[i] + rsum[i];
        }
#pragma unroll
        for (int nb = 0; nb < 16; ++nb)
#pragma unroll
          for (int i = 0; i < 4; ++i) O[m][nb][i] *= corr[i];
        // P (C-layout) -> wave-private LDS [32 q][64 kv], swizzled rows of 128B
        u16* Pw = (u16*)Plds[wid];
#pragma unroll
        for (int nb = 0; nb < 4; ++nb)
#pragma unroll
          for (int i = 0; i < 4; ++i) {
            int row = m * 16 + lg * 4 + i;
            Pw[(row * 128 + ((nb * 32 + l15 * 2) ^ ((row & 7) << 4))) >> 1] =
                f2bf(s[m][nb][i]);
          }
      }
      // PV: V fragment read once per (nb,ksv), reused across both m
      u16* Pw = (u16*)Plds[wid];
      bfrag pa[2][2];
#pragma unroll
      for (int m = 0; m < 2; ++m)
#pragma unroll
        for (int ksv = 0; ksv < 2; ++ksv) {
          int prow = m * 16 + l15;
          pa[m][ksv] = *(const bfrag*)&Pw[prow * 64 +
              (((ksv * 64 + lg * 16) ^ ((prow & 7) << 4)) >> 1)];
        }
#pragma unroll
      for (int nb = 0; nb < 16; ++nb) {
        int d = nb * 16 + l15;
#pragma unroll
        for (int ksv = 0; ksv < 2; ++ksv) {
          bfrag vb = *(const bfrag*)&Vb[d * 64 +
              (((ksv * 64 + lg * 16) ^ ((d & 7) << 4)) >> 1)];
#pragma unroll
          for (int m = 0; m < 2; ++m)
            O[m][nb] = __builtin_amdgcn_mfma_f32_16x16x32_bf16(pa[m][ksv], vb, O[m][nb], 0, 0, 0);
        }
      }
    }
  }
#pragma unroll
  for (int m = 0; m < 2; ++m) {
    float rinv[4];
#pragma unroll
    for (int i = 0; i < 4; ++i) rinv[i] = 1.f / lrow[m][i];
    u16* orow = ocat + (long long)(b * T_ + wrow0 + m * 16) * 1024 + h * 256;
#pragma unroll
    for (int nb = 0; nb < 16; ++nb)
#pragma unroll
      for (int i = 0; i < 4; ++i) {
        int row = lg * 4 + i;
        orow[(long long)row * 1024 + nb * 16 + l15] = f2bf(O[m][nb][i] * rinv[i]);
      }
  }
}

// ---------------------------------------------------------------- GEMM (NT), 2-phase dbuf
template <int BM, int BN, int LDOUT, int FLAGS, int SPLITK, int SWAP>
__global__ __launch_bounds__(256) void gemm_nt(
    const u16* __restrict__ A, int lda,
    const u16* __restrict__ B, int ldb,
    int K, void* outp, const float* __restrict__ bias) {
  constexpr int MR = BM / 32, NR = BN / 32;
  __shared__ u16 As[2][BM * 32];
  __shared__ u16 Bs[2][BN * 32];
  int gx = SWAP ? blockIdx.y : blockIdx.x;
  int gy = SWAP ? blockIdx.x : blockIdx.y;
  int z = blockIdx.z;
  const u16* Ab = A + (long long)gy * BM * lda + (SPLITK ? z * 256 : 0);
  const u16* Bb = B + (long long)gx * BN * ldb + (SPLITK ? z * 256 : 0);
  float* outf = (float*)outp + (SPLITK ? (long long)z * 1048576 : 0);
  u16* outh = (u16*)outp + (SPLITK ? (long long)z * 1048576 : 0);
  int tid = threadIdx.x;
  int lane = tid & 63, wid = tid >> 6;
  int wr = (wid >> 1) * (BM / 2), wc = (wid & 1) * (BN / 2);
  int srow = tid >> 2, scol = (tid & 3) * 8;

  auto stage = [&](int t, int bufi) {
    int k0 = t * 32;
#pragma unroll
    for (int i = 0; i < BM / 64; ++i)
      gload_lds16(Ab + (long long)(srow + i * 64) * lda + k0 + scol,
                  &As[bufi][(srow + i * 64) * 32 + scol]);
#pragma unroll
    for (int i = 0; i < BN / 64; ++i)
      gload_lds16(Bb + (long long)(srow + i * 64) * ldb + k0 + scol,
                  &Bs[bufi][(srow + i * 64) * 32 + scol]);
  };

  facc acc[MR][NR];
  facc zf = {0.f, 0.f, 0.f, 0.f};
#pragma unroll
  for (int m = 0; m < MR; ++m)
#pragma unroll
    for (int n = 0; n < NR; ++n) acc[m][n] = zf;

  int nt = K >> 5;
  stage(0, 0);
  __syncthreads();
  for (int t = 0; t < nt; ++t) {
    int cur = t & 1;
    if (t + 1 < nt) stage(t + 1, cur ^ 1);
    int kk = (lane >> 4) * 8;
    int ar = wr + (lane & 15);
    int br = wc + (lane & 15);
    bfrag af[MR], bfv[NR];
#pragma unroll
    for (int m = 0; m < MR; ++m) af[m] = *(const bfrag*)&As[cur][(ar + m * 16) * 32 + kk];
#pragma unroll
    for (int n = 0; n < NR; ++n) bfv[n] = *(const bfrag*)&Bs[cur][(br + n * 16) * 32 + kk];
#pragma unroll
    for (int m = 0; m < MR; ++m)
#pragma unroll
      for (int n = 0; n < NR; ++n)
        acc[m][n] = __builtin_amdgcn_mfma_f32_16x16x32_bf16(af[m], bfv[n], acc[m][n], 0, 0, 0);
    __syncthreads();
  }

  int rg = (lane >> 4) * 4;
  int cl = lane & 15;
  int rbase = gy * BM + wr + rg;
  int cbase = gx * BN + wc + cl;
#pragma unroll
  for (int m = 0; m < MR; ++m) {
#pragma unroll
    for (int n = 0; n < NR; ++n) {
      int c_abs = cbase + n * 16;
      float bvv = (FLAGS & FLAG_BIAS) ? bias[c_abs] : 0.f;
#pragma unroll
      for (int i = 0; i < 4; ++i) {
        int r = rbase + m * 16 + i;
        float val = acc[m][n][i] + bvv;
        if (FLAGS & FLAG_RELU) val = fmaxf(val, 0.f);
        int oi = r * LDOUT + c_abs;       // int32, LDOUT compile-time
        if (FLAGS & FLAG_BF16) outh[oi] = f2bf(val);
        else if (FLAGS & FLAG_NT) __builtin_nontemporal_store(val, &outf[oi]);
        else outf[oi] = val;
      }
    }
  }
}

// ---------------------------------------------------------------- launch
extern "C" void kernel_launch(void* const* d_in, const int* in_sizes, int n_in,
                              void* d_out, int out_size, void* d_ws, size_t ws_size,
                              hipStream_t stream) {
  (void)in_sizes; (void)n_in; (void)out_size; (void)ws_size;
  const int*   tokens = (const int*)d_in[0];
  const float* embed  = (const float*)d_in[1];
  const float* pos    = (const float*)d_in[2];
  const float* ln1_g  = (const float*)d_in[3];
  const float* ln1_b  = (const float*)d_in[4];
  const float* wq     = (const float*)d_in[5];
  const float* wk     = (const float*)d_in[6];
  const float* wv     = (const float*)d_in[7];
  const float* wo     = (const float*)d_in[8];
  const float* wo_b   = (const float*)d_in[9];
  const float* ln2_g  = (const float*)d_in[10];
  const float* ln2_b  = (const float*)d_in[11];
  const float* w1     = (const float*)d_in[12];
  const float* b1     = (const float*)d_in[13];
  const float* w2     = (const float*)d_in[14];
  const float* b2     = (const float*)d_in[15];
  const float* lnf_g  = (const float*)d_in[16];
  const float* lnf_b  = (const float*)d_in[17];
  const float* wf     = (const float*)d_in[18];
  const float* bf     = (const float*)d_in[19];
  float* out = (float*)d_out;

  char* ws = (char*)d_ws;
  size_t off = 0;
  auto alloc = [&](size_t bytes) -> char* {
    char* p = ws + off;
    off += (bytes + 255) & ~(size_t)255;
    return p;
  };
  const long long NR = (long long)B_ * T_;
  u16* xn    = (u16*)alloc(NR * C_ * 2);           // single bf16 residual stream
  u16* qkv   = (u16*)alloc(NR * 3072LL * 2);
  u16* vt    = (u16*)alloc((long long)B_ * H_ * C_ * T_ * 2);
  u16* ocat  = (u16*)alloc(NR * (long long)(H_ * C_) * 2);
  u16* hdn   = (u16*)alloc(NR * (long long)FF * 2);
  u16* pbuf  = (u16*)alloc(4LL * NR * C_ * 2);     // split-K partials bf16
  u16* wqkvT = (u16*)alloc((long long)L_ * 3 * H_ * C_ * C_ * 2);
  u16* woT   = (u16*)alloc((long long)L_ * C_ * (H_ * C_) * 2);
  u16* w1T   = (u16*)alloc((long long)L_ * FF * C_ * 2);
  u16* w2T   = (u16*)alloc((long long)L_ * C_ * FF * 2);
  u16* wfT   = (u16*)alloc((long long)V_ * C_ * 2);

  dim3 tb(256);

  transpose_all<<<dim3(14144), tb, 0, stream>>>(wq, wk, wv, wo, w1, w2, wf,
                                                wqkvT, woT, w1T, w2T, wfT);
  embed_ln<<<dim3(1024), tb, 0, stream>>>(tokens, embed, pos, xn, ln1_g, ln1_b);

  for (int l = 0; l < L_; ++l) {
    // QKV: [4096,256]@[3072,256]^T -> qkv [4096][3072]
    gemm_nt<64, 64, 3072, FLAG_BF16, 0, 0><<<dim3(48, 64, 1), tb, 0, stream>>>(
        xn, C_, wqkvT + (long long)l * 3 * 1024 * 256, C_, C_, qkv, nullptr);
    transpose_v<<<dim3(64, 8, 8), tb, 0, stream>>>(qkv, vt);
    flash_k<<<dim3(32, 8), dim3(128), 0, stream>>>(qkv, vt, ocat);
    // WO: split-K x4 -> pbuf bf16
    gemm_nt<64, 64, 256, FLAG_BF16, 1, 0><<<dim3(4, 64, 4), tb, 0, stream>>>(
        ocat, H_ * C_, woT + (long long)l * C_ * H_ * C_, H_ * C_, C_, pbuf, nullptr);
    reduce_ln<<<dim3(1024), tb, 0, stream>>>(pbuf, xn, wo_b + l * C_,
                                             ln2_g + l * C_, ln2_b + l * C_);
    // MLP1
    gemm_nt<64, 64, 1024, FLAG_BIAS | FLAG_RELU | FLAG_BF16, 0, 0>
        <<<dim3(16, 64, 1), tb, 0, stream>>>(
        xn, C_, w1T + (long long)l * FF * C_, C_, C_, hdn, b1 + l * FF);
    // MLP2: split-K x4 -> pbuf bf16
    gemm_nt<64, 64, 256, FLAG_BF16, 1, 0><<<dim3(4, 64, 4), tb, 0, stream>>>(
        hdn, FF, w2T + (long long)l * C_ * FF, FF, C_, pbuf, nullptr);
    const float* ng = (l < 3) ? (ln1_g + (l + 1) * C_) : lnf_g;
    const float* nb = (l < 3) ? (ln1_b + (l + 1) * C_) : lnf_b;
    reduce_ln<<<dim3(1024), tb, 0, stream>>>(pbuf, xn, b2 + l * C_, ng, nb);
  }
  // logits = xn @ wf + bf  (fp32, [4096][32000], nontemporal stores)
  gemm_nt<128, 128, 32000, FLAG_BIAS | FLAG_NT, 0, 1><<<dim3(32, 250, 1), tb, 0, stream>>>(
      xn, C_, wfT, C_, C_, out, bf);
}

// Round 13
// 788.799 us; speedup vs baseline: 1.4458x; 1.4458x over previous
//
#include <hip/hip_runtime.h>
#include <stdint.h>

#define B_ 2
#define T_ 2048
#define C_ 256
#define H_ 4
#define L_ 4
#define FF 1024
#define V_ 32000

typedef short bfrag __attribute__((ext_vector_type(8)));   // 8 x bf16 (MFMA A/B operand)
typedef float facc  __attribute__((ext_vector_type(4)));   // MFMA C/D
typedef short s4v   __attribute__((ext_vector_type(4)));
typedef short s8v   __attribute__((ext_vector_type(8)));
typedef unsigned short u16;

#define FLAG_BIAS 1
#define FLAG_RELU 4
#define FLAG_BF16 8
#define FLAG_NT   16

__device__ __forceinline__ u16 f2bf(float f) {
  uint32_t x = __float_as_uint(f);
  return (u16)((x + 0x7fffu + ((x >> 16) & 1u)) >> 16);
}
__device__ __forceinline__ float bf2f(u16 u) {
  return __uint_as_float(((uint32_t)u) << 16);
}

__device__ __forceinline__ void gload_lds16(const void* g, void* l) {
  __builtin_amdgcn_global_load_lds(
      (const __attribute__((address_space(1))) uint32_t*)g,
      (__attribute__((address_space(3))) uint32_t*)l, 16, 0, 0);
}

// ---------------------------------------------------------------- all weight transposes
__global__ __launch_bounds__(256) void transpose_all(
    const float* __restrict__ wq, const float* __restrict__ wk,
    const float* __restrict__ wv, const float* __restrict__ wo,
    const float* __restrict__ w1, const float* __restrict__ w2,
    const float* __restrict__ wf,
    u16* __restrict__ wqkvT, u16* __restrict__ woT, u16* __restrict__ w1T,
    u16* __restrict__ w2T, u16* __restrict__ wfT) {
  int bid = blockIdx.x;
  const float* in;
  u16* out;
  int R, Cc, cx, ry;
  long long zi, zo;
  if (bid < 3072) {              // wq/wk/wv: [16][256][256] -> wqkvT [L][3][1024][256]
    int job = bid >> 10, w = bid & 1023;
    int z = w >> 6, t = w & 63;
    cx = t & 7; ry = t >> 3; R = 256; Cc = 256;
    in = (job == 0 ? wq : job == 1 ? wk : wv);
    zi = (long long)z * 65536;
    zo = (long long)(z >> 2) * 786432 + (long long)(z & 3) * 65536
       + (long long)job * 262144;
    out = wqkvT;
  } else if (bid < 4096) {       // wo: [4][1024][256] -> [4][256][1024]
    int w = bid - 3072; int z = w >> 8, t = w & 255;
    cx = t & 7; ry = t >> 3; R = 1024; Cc = 256;
    in = wo; zi = (long long)z * 262144; zo = zi; out = woT;
  } else if (bid < 5120) {       // w1: [4][256][1024] -> [4][1024][256]
    int w = bid - 4096; int z = w >> 8, t = w & 255;
    cx = t & 31; ry = t >> 5; R = 256; Cc = 1024;
    in = w1; zi = (long long)z * 262144; zo = zi; out = w1T;
  } else if (bid < 6144) {       // w2: [4][1024][256] -> [4][256][1024]
    int w = bid - 5120; int z = w >> 8, t = w & 255;
    cx = t & 7; ry = t >> 3; R = 1024; Cc = 256;
    in = w2; zi = (long long)z * 262144; zo = zi; out = w2T;
  } else {                       // wf: [256][32000] -> [32000][256]
    int t = bid - 6144; cx = t % 1000; ry = t / 1000;
    R = 256; Cc = 32000; in = wf; zi = 0; zo = 0; out = wfT;
  }
  __shared__ float tile[32][33];
  int c0 = cx * 32, r0 = ry * 32;
  int tx = threadIdx.x & 31, ty = threadIdx.x >> 5;
#pragma unroll
  for (int i = ty; i < 32; i += 8)
    tile[i][tx] = in[zi + (long long)(r0 + i) * Cc + (c0 + tx)];
  __syncthreads();
#pragma unroll
  for (int i = ty; i < 32; i += 8)
    out[zo + (long long)(c0 + i) * R + (r0 + tx)] = f2bf(tile[tx][i]);
}

// ---------------------------------------------------------------- V transpose (u16)
__global__ __launch_bounds__(256) void transpose_v(const u16* __restrict__ qkv,
                                                   u16* __restrict__ vt) {
  __shared__ u16 tile[32][33];
  int z = blockIdx.z, b = z >> 2, h = z & 3;
  const u16* in = qkv + (long long)b * T_ * 3072 + 2048 + h * 256;
  int t0 = blockIdx.x * 32, d0 = blockIdx.y * 32;
  int tx = threadIdx.x & 31, ty = threadIdx.x >> 5;
#pragma unroll
  for (int i = ty; i < 32; i += 8)
    tile[i][tx] = in[(long long)(t0 + i) * 3072 + (d0 + tx)];
  __syncthreads();
#pragma unroll
  for (int i = ty; i < 32; i += 8)
    vt[((long long)z * 256 + d0 + i) * T_ + (t0 + tx)] = tile[tx][i];
}

// ---------------------------------------------------------------- embed + LN1(l=0) fused
__global__ __launch_bounds__(256) void embed_ln(const int* __restrict__ tok,
                                                const float* __restrict__ emb,
                                                const float* __restrict__ pos,
                                                u16* __restrict__ xn,
                                                const float* __restrict__ g,
                                                const float* __restrict__ b) {
  int wid = threadIdx.x >> 6, lane = threadIdx.x & 63;
  int row = blockIdx.x * 4 + wid;
  int t = row & (T_ - 1);
  float4 ev = ((const float4*)(emb + (long long)tok[row] * C_))[lane];
  float4 pv = ((const float4*)(pos + (long long)t * C_))[lane];
  float4 v;
  v.x = ev.x + pv.x; v.y = ev.y + pv.y; v.z = ev.z + pv.z; v.w = ev.w + pv.w;
  float s = v.x + v.y + v.z + v.w;
#pragma unroll
  for (int o = 32; o > 0; o >>= 1) s += __shfl_xor(s, o);
  float mean = s * (1.f / 256.f);
  float d0 = v.x - mean, d1 = v.y - mean, d2 = v.z - mean, d3 = v.w - mean;
  float q2 = d0 * d0 + d1 * d1 + d2 * d2 + d3 * d3;
#pragma unroll
  for (int o = 32; o > 0; o >>= 1) q2 += __shfl_xor(q2, o);
  float rstd = rsqrtf(q2 * (1.f / 256.f) + 1e-5f);
  float4 gv = ((const float4*)g)[lane];
  float4 bv = ((const float4*)b)[lane];
  u16 tmp[4] = {f2bf(d0 * rstd * gv.x + bv.x), f2bf(d1 * rstd * gv.y + bv.y),
                f2bf(d2 * rstd * gv.z + bv.z), f2bf(d3 * rstd * gv.w + bv.w)};
  *(s4v*)&xn[(long long)row * C_ + lane * 4] = *(const s4v*)tmp;
}

// ---------------------------------------------------------------- split-K reduce (bf16 partials) + bias + residual + LN
__global__ __launch_bounds__(256) void reduce_ln(const u16* __restrict__ pbuf,
                                                 u16* __restrict__ xn,
                                                 const float* __restrict__ bias,
                                                 const float* __restrict__ g,
                                                 const float* __restrict__ b) {
  int wid = threadIdx.x >> 6, lane = threadIdx.x & 63;
  long long row = (long long)blockIdx.x * 4 + wid;
  const u16* p = pbuf + row * C_ + lane * 4;
  const int SL = 1048576;
  s4v rv = *(const s4v*)&xn[row * C_ + lane * 4];
  float4 bi = ((const float4*)bias)[lane];
  float4 v;
  v.x = bf2f((u16)rv[0]) + bi.x;
  v.y = bf2f((u16)rv[1]) + bi.y;
  v.z = bf2f((u16)rv[2]) + bi.z;
  v.w = bf2f((u16)rv[3]) + bi.w;
#pragma unroll
  for (int sI = 0; sI < 4; ++sI) {
    s4v pv = *(const s4v*)(p + sI * SL);
    v.x += bf2f((u16)pv[0]);
    v.y += bf2f((u16)pv[1]);
    v.z += bf2f((u16)pv[2]);
    v.w += bf2f((u16)pv[3]);
  }
  float s = v.x + v.y + v.z + v.w;
#pragma unroll
  for (int o = 32; o > 0; o >>= 1) s += __shfl_xor(s, o);
  float mean = s * (1.f / 256.f);
  float d0 = v.x - mean, d1 = v.y - mean, d2 = v.z - mean, d3 = v.w - mean;
  float q2 = d0 * d0 + d1 * d1 + d2 * d2 + d3 * d3;
#pragma unroll
  for (int o = 32; o > 0; o >>= 1) q2 += __shfl_xor(q2, o);
  float rstd = rsqrtf(q2 * (1.f / 256.f) + 1e-5f);
  float4 gv = ((const float4*)g)[lane];
  float4 bv = ((const float4*)b)[lane];
  u16 tmp[4] = {f2bf(d0 * rstd * gv.x + bv.x), f2bf(d1 * rstd * gv.y + bv.y),
                f2bf(d2 * rstd * gv.z + bv.z), f2bf(d3 * rstd * gv.w + bv.w)};
  *(s4v*)&xn[row * C_ + lane * 4] = *(const s4v*)tmp;
}

// ---------------------------------------------------------------- flash attention (R11 4-wave version)
__global__ __launch_bounds__(256, 1) void flash_k(const u16* __restrict__ qkv,
                                                  const u16* __restrict__ vt,
                                                  u16* __restrict__ ocat) {
  __shared__ u16 Klds[2][64 * 256];
  __shared__ u16 Vlds[2][256 * 64];
  __shared__ u16 Plds[4][1024];
  int ib = blockIdx.x, z = blockIdx.y;
  int b = z >> 2, h = z & 3;
  int lo0 = ib * 32, hi0 = 2016 - ib * 32;
  int tid = threadIdx.x, lane = tid & 63, wid = tid >> 6;
  int l15 = lane & 15, lg = lane >> 4;
  int wrow0 = (wid < 2) ? (lo0 + wid * 16) : (hi0 + (wid - 2) * 16);
  int jmax = (hi0 + 31) >> 6;

  bfrag qf[8];
  {
    const u16* qrow = qkv + (long long)(b * T_ + wrow0 + l15) * 3072 + h * 256 + lg * 8;
#pragma unroll
    for (int ks = 0; ks < 8; ++ks) qf[ks] = *(const bfrag*)(qrow + ks * 32);
  }
  facc zf = {0.f, 0.f, 0.f, 0.f};
  facc O[16];
#pragma unroll
  for (int nb = 0; nb < 16; ++nb) O[nb] = zf;
  float mrow[4] = {-1e30f, -1e30f, -1e30f, -1e30f};
  float lrow[4] = {0.f, 0.f, 0.f, 0.f};

  const u16* kgbase = qkv + (long long)(b * T_) * 3072 + 1024 + h * 256;
  const u16* vgbase = vt + (long long)z * 256 * 2048;

  auto stage = [&](int j) {
    int kv0 = j * 64;
    int bufi = j & 1;
#pragma unroll
    for (int c = 0; c < 8; ++c) {
      int chunk = wid * 8 + c;
      int krow = chunk * 2 + (lane >> 5);
      int kcb = ((lane & 31) * 16) ^ ((krow & 7) << 4);
      gload_lds16(kgbase + (long long)(kv0 + krow) * 3072 + (kcb >> 1),
                  &Klds[bufi][chunk * 512 + lane * 8]);
      int drow = chunk * 8 + (lane >> 3);
      int vcb = ((lane & 7) * 16) ^ ((drow & 7) << 4);
      gload_lds16(vgbase + (long long)drow * 2048 + kv0 + (vcb >> 1),
                  &Vlds[bufi][chunk * 512 + lane * 8]);
    }
  };

  stage(0);
  for (int j = 0; j <= jmax; ++j) {
    __syncthreads();
    if (j < jmax) stage(j + 1);
    const u16* Kb = Klds[j & 1];
    const u16* Vb = Vlds[j & 1];
    int kv0 = j * 64;
    bool skip = (kv0 > wrow0 + 15);
    if (!skip) {
      bool full = (kv0 + 63 <= wrow0);
      facc s[4];
#pragma unroll
      for (int nb = 0; nb < 4; ++nb) {
        s[nb] = zf;
#pragma unroll
        for (int ks = 0; ks < 8; ++ks) {
          int row = nb * 16 + l15;
          bfrag kb = *(const bfrag*)&Kb[row * 256 +
              (((ks * 64 + lg * 16) ^ ((row & 7) << 4)) >> 1)];
          s[nb] = __builtin_amdgcn_mfma_f32_16x16x32_bf16(qf[ks], kb, s[nb], 0, 0, 0);
        }
      }
      float pmax[4] = {-1e30f, -1e30f, -1e30f, -1e30f};
#pragma unroll
      for (int nb = 0; nb < 4; ++nb) {
        int col = kv0 + nb * 16 + l15;
#pragma unroll
        for (int i = 0; i < 4; ++i) {
          float vsc = s[nb][i] * 0.0625f;
          int rowa = wrow0 + lg * 4 + i;
          if (!full && col > rowa) vsc = -1e30f;
          s[nb][i] = vsc;
          pmax[i] = fmaxf(pmax[i], vsc);
        }
      }
#pragma unroll
      for (int i = 0; i < 4; ++i) {
        pmax[i] = fmaxf(pmax[i], __shfl_xor(pmax[i], 1));
        pmax[i] = fmaxf(pmax[i], __shfl_xor(pmax[i], 2));
        pmax[i] = fmaxf(pmax[i], __shfl_xor(pmax[i], 4));
        pmax[i] = fmaxf(pmax[i], __shfl_xor(pmax[i], 8));
      }
      float corr[4], rsum[4];
#pragma unroll
      for (int i = 0; i < 4; ++i) {
        float mn = fmaxf(mrow[i], pmax[i]);
        corr[i] = __expf(mrow[i] - mn);
        mrow[i] = mn;
        rsum[i] = 0.f;
      }
#pragma unroll
      for (int nb = 0; nb < 4; ++nb)
#pragma unroll
        for (int i = 0; i < 4; ++i) {
          float p = __expf(s[nb][i] - mrow[i]);
          s[nb][i] = p;
          rsum[i] += p;
        }
#pragma unroll
      for (int i = 0; i < 4; ++i) {
        rsum[i] += __shfl_xor(rsum[i], 1);
        rsum[i] += __shfl_xor(rsum[i], 2);
        rsum[i] += __shfl_xor(rsum[i], 4);
        rsum[i] += __shfl_xor(rsum[i], 8);
        lrow[i] = lrow[i] * corr[i] + rsum[i];
      }
#pragma unroll
      for (int nb = 0; nb < 16; ++nb)
#pragma unroll
        for (int i = 0; i < 4; ++i) O[nb][i] *= corr[i];
      u16* Pw = (u16*)Plds[wid];
#pragma unroll
      for (int nb = 0; nb < 4; ++nb)
#pragma unroll
        for (int i = 0; i < 4; ++i) {
          int row = lg * 4 + i;
          Pw[(row * 128 + ((nb * 32 + l15 * 2) ^ ((row & 7) << 4))) >> 1] =
              f2bf(s[nb][i]);
        }
      bfrag pa[2];
#pragma unroll
      for (int ksv = 0; ksv < 2; ++ksv)
        pa[ksv] = *(const bfrag*)&Pw[l15 * 64 +
            (((ksv * 64 + lg * 16) ^ ((l15 & 7) << 4)) >> 1)];
#pragma unroll
      for (int nb = 0; nb < 16; ++nb) {
        int d = nb * 16 + l15;
#pragma unroll
        for (int ksv = 0; ksv < 2; ++ksv) {
          bfrag vb = *(const bfrag*)&Vb[d * 64 +
              (((ksv * 64 + lg * 16) ^ ((d & 7) << 4)) >> 1)];
          O[nb] = __builtin_amdgcn_mfma_f32_16x16x32_bf16(pa[ksv], vb, O[nb], 0, 0, 0);
        }
      }
    }
  }
  float rinv[4];
#pragma unroll
  for (int i = 0; i < 4; ++i) rinv[i] = 1.f / lrow[i];
  u16* orow = ocat + (long long)(b * T_ + wrow0) * 1024 + h * 256;
#pragma unroll
  for (int nb = 0; nb < 16; ++nb)
#pragma unroll
    for (int i = 0; i < 4; ++i) {
      int row = lg * 4 + i;
      orow[(long long)row * 1024 + nb * 16 + l15] = f2bf(O[nb][i] * rinv[i]);
    }
}

// ---------------------------------------------------------------- GEMM (NT), 2-phase dbuf
template <int BM, int BN, int LDOUT, int FLAGS, int SPLITK, int SWAP>
__global__ __launch_bounds__(256) void gemm_nt(
    const u16* __restrict__ A, int lda,
    const u16* __restrict__ B, int ldb,
    int K, void* outp, const float* __restrict__ bias) {
  constexpr int MR = BM / 32, NR = BN / 32;
  __shared__ u16 As[2][BM * 32];
  __shared__ u16 Bs[2][BN * 32];
  int gx = SWAP ? blockIdx.y : blockIdx.x;
  int gy = SWAP ? blockIdx.x : blockIdx.y;
  int z = blockIdx.z;
  const u16* Ab = A + (long long)gy * BM * lda + (SPLITK ? z * 256 : 0);
  const u16* Bb = B + (long long)gx * BN * ldb + (SPLITK ? z * 256 : 0);
  float* outf = (float*)outp + (SPLITK ? (long long)z * 1048576 : 0);
  u16* outh = (u16*)outp + (SPLITK ? (long long)z * 1048576 : 0);
  int tid = threadIdx.x;
  int lane = tid & 63, wid = tid >> 6;
  int wr = (wid >> 1) * (BM / 2), wc = (wid & 1) * (BN / 2);
  int srow = tid >> 2, scol = (tid & 3) * 8;

  auto stage = [&](int t, int bufi) {
    int k0 = t * 32;
#pragma unroll
    for (int i = 0; i < BM / 64; ++i)
      gload_lds16(Ab + (long long)(srow + i * 64) * lda + k0 + scol,
                  &As[bufi][(srow + i * 64) * 32 + scol]);
#pragma unroll
    for (int i = 0; i < BN / 64; ++i)
      gload_lds16(Bb + (long long)(srow + i * 64) * ldb + k0 + scol,
                  &Bs[bufi][(srow + i * 64) * 32 + scol]);
  };

  facc acc[MR][NR];
  facc zf = {0.f, 0.f, 0.f, 0.f};
#pragma unroll
  for (int m = 0; m < MR; ++m)
#pragma unroll
    for (int n = 0; n < NR; ++n) acc[m][n] = zf;

  int nt = K >> 5;
  stage(0, 0);
  __syncthreads();
  for (int t = 0; t < nt; ++t) {
    int cur = t & 1;
    if (t + 1 < nt) stage(t + 1, cur ^ 1);
    int kk = (lane >> 4) * 8;
    int ar = wr + (lane & 15);
    int br = wc + (lane & 15);
    bfrag af[MR], bfv[NR];
#pragma unroll
    for (int m = 0; m < MR; ++m) af[m] = *(const bfrag*)&As[cur][(ar + m * 16) * 32 + kk];
#pragma unroll
    for (int n = 0; n < NR; ++n) bfv[n] = *(const bfrag*)&Bs[cur][(br + n * 16) * 32 + kk];
#pragma unroll
    for (int m = 0; m < MR; ++m)
#pragma unroll
      for (int n = 0; n < NR; ++n)
        acc[m][n] = __builtin_amdgcn_mfma_f32_16x16x32_bf16(af[m], bfv[n], acc[m][n], 0, 0, 0);
    __syncthreads();
  }

  int rg = (lane >> 4) * 4;
  int cl = lane & 15;
  int rbase = gy * BM + wr + rg;
  int cbase = gx * BN + wc + cl;
#pragma unroll
  for (int m = 0; m < MR; ++m) {
#pragma unroll
    for (int n = 0; n < NR; ++n) {
      int c_abs = cbase + n * 16;
      float bvv = (FLAGS & FLAG_BIAS) ? bias[c_abs] : 0.f;
#pragma unroll
      for (int i = 0; i < 4; ++i) {
        int r = rbase + m * 16 + i;
        float val = acc[m][n][i] + bvv;
        if (FLAGS & FLAG_RELU) val = fmaxf(val, 0.f);
        int oi = r * LDOUT + c_abs;       // int32, LDOUT compile-time
        if (FLAGS & FLAG_BF16) outh[oi] = f2bf(val);
        else if (FLAGS & FLAG_NT) __builtin_nontemporal_store(val, &outf[oi]);
        else outf[oi] = val;
      }
    }
  }
}

// ---------------------------------------------------------------- launch
extern "C" void kernel_launch(void* const* d_in, const int* in_sizes, int n_in,
                              void* d_out, int out_size, void* d_ws, size_t ws_size,
                              hipStream_t stream) {
  (void)in_sizes; (void)n_in; (void)out_size; (void)ws_size;
  const int*   tokens = (const int*)d_in[0];
  const float* embed  = (const float*)d_in[1];
  const float* pos    = (const float*)d_in[2];
  const float* ln1_g  = (const float*)d_in[3];
  const float* ln1_b  = (const float*)d_in[4];
  const float* wq     = (const float*)d_in[5];
  const float* wk     = (const float*)d_in[6];
  const float* wv     = (const float*)d_in[7];
  const float* wo     = (const float*)d_in[8];
  const float* wo_b   = (const float*)d_in[9];
  const float* ln2_g  = (const float*)d_in[10];
  const float* ln2_b  = (const float*)d_in[11];
  const float* w1     = (const float*)d_in[12];
  const float* b1     = (const float*)d_in[13];
  const float* w2     = (const float*)d_in[14];
  const float* b2     = (const float*)d_in[15];
  const float* lnf_g  = (const float*)d_in[16];
  const float* lnf_b  = (const float*)d_in[17];
  const float* wf     = (const float*)d_in[18];
  const float* bf     = (const float*)d_in[19];
  float* out = (float*)d_out;

  char* ws = (char*)d_ws;
  size_t off = 0;
  auto alloc = [&](size_t bytes) -> char* {
    char* p = ws + off;
    off += (bytes + 255) & ~(size_t)255;
    return p;
  };
  const long long NR = (long long)B_ * T_;
  u16* xn    = (u16*)alloc(NR * C_ * 2);           // single bf16 residual stream
  u16* qkv   = (u16*)alloc(NR * 3072LL * 2);
  u16* vt    = (u16*)alloc((long long)B_ * H_ * C_ * T_ * 2);
  u16* ocat  = (u16*)alloc(NR * (long long)(H_ * C_) * 2);
  u16* hdn   = (u16*)alloc(NR * (long long)FF * 2);
  u16* pbuf  = (u16*)alloc(4LL * NR * C_ * 2);     // split-K partials bf16
  u16* wqkvT = (u16*)alloc((long long)L_ * 3 * H_ * C_ * C_ * 2);
  u16* woT   = (u16*)alloc((long long)L_ * C_ * (H_ * C_) * 2);
  u16* w1T   = (u16*)alloc((long long)L_ * FF * C_ * 2);
  u16* w2T   = (u16*)alloc((long long)L_ * C_ * FF * 2);
  u16* wfT   = (u16*)alloc((long long)V_ * C_ * 2);

  dim3 tb(256);

  transpose_all<<<dim3(14144), tb, 0, stream>>>(wq, wk, wv, wo, w1, w2, wf,
                                                wqkvT, woT, w1T, w2T, wfT);
  embed_ln<<<dim3(1024), tb, 0, stream>>>(tokens, embed, pos, xn, ln1_g, ln1_b);

  for (int l = 0; l < L_; ++l) {
    // QKV: [4096,256]@[3072,256]^T -> qkv [4096][3072]; 128x128 tile, 768 blocks (~3/CU)
    gemm_nt<128, 128, 3072, FLAG_BF16, 0, 0><<<dim3(24, 32, 1), tb, 0, stream>>>(
        xn, C_, wqkvT + (long long)l * 3 * 1024 * 256, C_, C_, qkv, nullptr);
    transpose_v<<<dim3(64, 8, 8), tb, 0, stream>>>(qkv, vt);
    flash_k<<<dim3(32, 8), tb, 0, stream>>>(qkv, vt, ocat);
    // WO: split-K x4 -> pbuf bf16
    gemm_nt<64, 64, 256, FLAG_BF16, 1, 0><<<dim3(4, 64, 4), tb, 0, stream>>>(
        ocat, H_ * C_, woT + (long long)l * C_ * H_ * C_, H_ * C_, C_, pbuf, nullptr);
    reduce_ln<<<dim3(1024), tb, 0, stream>>>(pbuf, xn, wo_b + l * C_,
                                             ln2_g + l * C_, ln2_b + l * C_);
    // MLP1
    gemm_nt<64, 64, 1024, FLAG_BIAS | FLAG_RELU | FLAG_BF16, 0, 0>
        <<<dim3(16, 64, 1), tb, 0, stream>>>(
        xn, C_, w1T + (long long)l * FF * C_, C_, C_, hdn, b1 + l * FF);
    // MLP2: split-K x4 -> pbuf bf16
    gemm_nt<64, 64, 256, FLAG_BF16, 1, 0><<<dim3(4, 64, 4), tb, 0, stream>>>(
        hdn, FF, w2T + (long long)l * C_ * FF, FF, C_, pbuf, nullptr);
    const float* ng = (l < 3) ? (ln1_g + (l + 1) * C_) : lnf_g;
    const float* nb = (l < 3) ? (ln1_b + (l + 1) * C_) : lnf_b;
    reduce_ln<<<dim3(1024), tb, 0, stream>>>(pbuf, xn, b2 + l * C_, ng, nb);
  }
  // logits = xn @ wf + bf  (fp32, [4096][32000], nontemporal stores)
  gemm_nt<128, 128, 32000, FLAG_BIAS | FLAG_NT, 0, 1><<<dim3(32, 250, 1), tb, 0, stream>>>(
      xn, C_, wfT, C_, C_, out, bf);
}

// Round 14
// 782.374 us; speedup vs baseline: 1.4576x; 1.0082x over previous
//
#include <hip/hip_runtime.h>
#include <stdint.h>

#define B_ 2
#define T_ 2048
#define C_ 256
#define H_ 4
#define L_ 4
#define FF 1024
#define V_ 32000

typedef short bfrag __attribute__((ext_vector_type(8)));   // 8 x bf16 (MFMA A/B operand)
typedef float facc  __attribute__((ext_vector_type(4)));   // MFMA C/D
typedef short s4v   __attribute__((ext_vector_type(4)));
typedef short s8v   __attribute__((ext_vector_type(8)));
typedef unsigned short u16;

#define FLAG_BIAS 1
#define FLAG_RELU 4
#define FLAG_BF16 8
#define FLAG_NT   16

__device__ __forceinline__ u16 f2bf(float f) {
  uint32_t x = __float_as_uint(f);
  return (u16)((x + 0x7fffu + ((x >> 16) & 1u)) >> 16);
}
__device__ __forceinline__ float bf2f(u16 u) {
  return __uint_as_float(((uint32_t)u) << 16);
}

__device__ __forceinline__ void gload_lds16(const void* g, void* l) {
  __builtin_amdgcn_global_load_lds(
      (const __attribute__((address_space(1))) uint32_t*)g,
      (__attribute__((address_space(3))) uint32_t*)l, 16, 0, 0);
}

// ---------------------------------------------------------------- all weight transposes
__global__ __launch_bounds__(256) void transpose_all(
    const float* __restrict__ wq, const float* __restrict__ wk,
    const float* __restrict__ wv, const float* __restrict__ wo,
    const float* __restrict__ w1, const float* __restrict__ w2,
    const float* __restrict__ wf,
    u16* __restrict__ wqkvT, u16* __restrict__ woT, u16* __restrict__ w1T,
    u16* __restrict__ w2T, u16* __restrict__ wfT) {
  int bid = blockIdx.x;
  const float* in;
  u16* out;
  int R, Cc, cx, ry;
  long long zi, zo;
  if (bid < 3072) {              // wq/wk/wv: [16][256][256] -> wqkvT [L][3][1024][256]
    int job = bid >> 10, w = bid & 1023;
    int z = w >> 6, t = w & 63;
    cx = t & 7; ry = t >> 3; R = 256; Cc = 256;
    in = (job == 0 ? wq : job == 1 ? wk : wv);
    zi = (long long)z * 65536;
    zo = (long long)(z >> 2) * 786432 + (long long)(z & 3) * 65536
       + (long long)job * 262144;
    out = wqkvT;
  } else if (bid < 4096) {       // wo: [4][1024][256] -> [4][256][1024]
    int w = bid - 3072; int z = w >> 8, t = w & 255;
    cx = t & 7; ry = t >> 3; R = 1024; Cc = 256;
    in = wo; zi = (long long)z * 262144; zo = zi; out = woT;
  } else if (bid < 5120) {       // w1: [4][256][1024] -> [4][1024][256]
    int w = bid - 4096; int z = w >> 8, t = w & 255;
    cx = t & 31; ry = t >> 5; R = 256; Cc = 1024;
    in = w1; zi = (long long)z * 262144; zo = zi; out = w1T;
  } else if (bid < 6144) {       // w2: [4][1024][256] -> [4][256][1024]
    int w = bid - 5120; int z = w >> 8, t = w & 255;
    cx = t & 7; ry = t >> 3; R = 1024; Cc = 256;
    in = w2; zi = (long long)z * 262144; zo = zi; out = w2T;
  } else {                       // wf: [256][32000] -> [32000][256]
    int t = bid - 6144; cx = t % 1000; ry = t / 1000;
    R = 256; Cc = 32000; in = wf; zi = 0; zo = 0; out = wfT;
  }
  __shared__ float tile[32][33];
  int c0 = cx * 32, r0 = ry * 32;
  int tx = threadIdx.x & 31, ty = threadIdx.x >> 5;
#pragma unroll
  for (int i = ty; i < 32; i += 8)
    tile[i][tx] = in[zi + (long long)(r0 + i) * Cc + (c0 + tx)];
  __syncthreads();
#pragma unroll
  for (int i = ty; i < 32; i += 8)
    out[zo + (long long)(c0 + i) * R + (r0 + tx)] = f2bf(tile[tx][i]);
}

// ---------------------------------------------------------------- V transpose (u16)
__global__ __launch_bounds__(256) void transpose_v(const u16* __restrict__ qkv,
                                                   u16* __restrict__ vt) {
  __shared__ u16 tile[32][33];
  int z = blockIdx.z, b = z >> 2, h = z & 3;
  const u16* in = qkv + (long long)b * T_ * 3072 + 2048 + h * 256;
  int t0 = blockIdx.x * 32, d0 = blockIdx.y * 32;
  int tx = threadIdx.x & 31, ty = threadIdx.x >> 5;
#pragma unroll
  for (int i = ty; i < 32; i += 8)
    tile[i][tx] = in[(long long)(t0 + i) * 3072 + (d0 + tx)];
  __syncthreads();
#pragma unroll
  for (int i = ty; i < 32; i += 8)
    vt[((long long)z * 256 + d0 + i) * T_ + (t0 + tx)] = tile[tx][i];
}

// ---------------------------------------------------------------- embed + LN1(l=0) fused
__global__ __launch_bounds__(256) void embed_ln(const int* __restrict__ tok,
                                                const float* __restrict__ emb,
                                                const float* __restrict__ pos,
                                                u16* __restrict__ xn,
                                                const float* __restrict__ g,
                                                const float* __restrict__ b) {
  int wid = threadIdx.x >> 6, lane = threadIdx.x & 63;
  int row = blockIdx.x * 4 + wid;
  int t = row & (T_ - 1);
  float4 ev = ((const float4*)(emb + (long long)tok[row] * C_))[lane];
  float4 pv = ((const float4*)(pos + (long long)t * C_))[lane];
  float4 v;
  v.x = ev.x + pv.x; v.y = ev.y + pv.y; v.z = ev.z + pv.z; v.w = ev.w + pv.w;
  float s = v.x + v.y + v.z + v.w;
#pragma unroll
  for (int o = 32; o > 0; o >>= 1) s += __shfl_xor(s, o);
  float mean = s * (1.f / 256.f);
  float d0 = v.x - mean, d1 = v.y - mean, d2 = v.z - mean, d3 = v.w - mean;
  float q2 = d0 * d0 + d1 * d1 + d2 * d2 + d3 * d3;
#pragma unroll
  for (int o = 32; o > 0; o >>= 1) q2 += __shfl_xor(q2, o);
  float rstd = rsqrtf(q2 * (1.f / 256.f) + 1e-5f);
  float4 gv = ((const float4*)g)[lane];
  float4 bv = ((const float4*)b)[lane];
  u16 tmp[4] = {f2bf(d0 * rstd * gv.x + bv.x), f2bf(d1 * rstd * gv.y + bv.y),
                f2bf(d2 * rstd * gv.z + bv.z), f2bf(d3 * rstd * gv.w + bv.w)};
  *(s4v*)&xn[(long long)row * C_ + lane * 4] = *(const s4v*)tmp;
}

// ---------------------------------------------------------------- split-K reduce (bf16 partials) + bias + residual + LN
__global__ __launch_bounds__(256) void reduce_ln(const u16* __restrict__ pbuf,
                                                 u16* __restrict__ xn,
                                                 const float* __restrict__ bias,
                                                 const float* __restrict__ g,
                                                 const float* __restrict__ b) {
  int wid = threadIdx.x >> 6, lane = threadIdx.x & 63;
  long long row = (long long)blockIdx.x * 4 + wid;
  const u16* p = pbuf + row * C_ + lane * 4;
  const int SL = 1048576;
  s4v rv = *(const s4v*)&xn[row * C_ + lane * 4];
  float4 bi = ((const float4*)bias)[lane];
  float4 v;
  v.x = bf2f((u16)rv[0]) + bi.x;
  v.y = bf2f((u16)rv[1]) + bi.y;
  v.z = bf2f((u16)rv[2]) + bi.z;
  v.w = bf2f((u16)rv[3]) + bi.w;
#pragma unroll
  for (int sI = 0; sI < 4; ++sI) {
    s4v pv = *(const s4v*)(p + sI * SL);
    v.x += bf2f((u16)pv[0]);
    v.y += bf2f((u16)pv[1]);
    v.z += bf2f((u16)pv[2]);
    v.w += bf2f((u16)pv[3]);
  }
  float s = v.x + v.y + v.z + v.w;
#pragma unroll
  for (int o = 32; o > 0; o >>= 1) s += __shfl_xor(s, o);
  float mean = s * (1.f / 256.f);
  float d0 = v.x - mean, d1 = v.y - mean, d2 = v.z - mean, d3 = v.w - mean;
  float q2 = d0 * d0 + d1 * d1 + d2 * d2 + d3 * d3;
#pragma unroll
  for (int o = 32; o > 0; o >>= 1) q2 += __shfl_xor(q2, o);
  float rstd = rsqrtf(q2 * (1.f / 256.f) + 1e-5f);
  float4 gv = ((const float4*)g)[lane];
  float4 bv = ((const float4*)b)[lane];
  u16 tmp[4] = {f2bf(d0 * rstd * gv.x + bv.x), f2bf(d1 * rstd * gv.y + bv.y),
                f2bf(d2 * rstd * gv.z + bv.z), f2bf(d3 * rstd * gv.w + bv.w)};
  *(s4v*)&xn[row * C_ + lane * 4] = *(const s4v*)tmp;
}

// ---------------------------------------------------------------- flash attention (R11 4-wave)
// 1D grid 256, z-affinity swizzle: z = bid & 7, ib = bid >> 3 -> all 32 blocks of a
// (b,h) land on one XCD (round-robin dispatch), K/V (2 MB) stays L2-resident.
__global__ __launch_bounds__(256, 1) void flash_k(const u16* __restrict__ qkv,
                                                  const u16* __restrict__ vt,
                                                  u16* __restrict__ ocat) {
  __shared__ u16 Klds[2][64 * 256];
  __shared__ u16 Vlds[2][256 * 64];
  __shared__ u16 Plds[4][1024];
  int bid = blockIdx.x;
  int z = bid & 7, ib = bid >> 3;
  int b = z >> 2, h = z & 3;
  int lo0 = ib * 32, hi0 = 2016 - ib * 32;
  int tid = threadIdx.x, lane = tid & 63, wid = tid >> 6;
  int l15 = lane & 15, lg = lane >> 4;
  int wrow0 = (wid < 2) ? (lo0 + wid * 16) : (hi0 + (wid - 2) * 16);
  int jmax = (hi0 + 31) >> 6;

  bfrag qf[8];
  {
    const u16* qrow = qkv + (long long)(b * T_ + wrow0 + l15) * 3072 + h * 256 + lg * 8;
#pragma unroll
    for (int ks = 0; ks < 8; ++ks) qf[ks] = *(const bfrag*)(qrow + ks * 32);
  }
  facc zf = {0.f, 0.f, 0.f, 0.f};
  facc O[16];
#pragma unroll
  for (int nb = 0; nb < 16; ++nb) O[nb] = zf;
  float mrow[4] = {-1e30f, -1e30f, -1e30f, -1e30f};
  float lrow[4] = {0.f, 0.f, 0.f, 0.f};

  const u16* kgbase = qkv + (long long)(b * T_) * 3072 + 1024 + h * 256;
  const u16* vgbase = vt + (long long)z * 256 * 2048;

  auto stage = [&](int j) {
    int kv0 = j * 64;
    int bufi = j & 1;
#pragma unroll
    for (int c = 0; c < 8; ++c) {
      int chunk = wid * 8 + c;
      int krow = chunk * 2 + (lane >> 5);
      int kcb = ((lane & 31) * 16) ^ ((krow & 7) << 4);
      gload_lds16(kgbase + (long long)(kv0 + krow) * 3072 + (kcb >> 1),
                  &Klds[bufi][chunk * 512 + lane * 8]);
      int drow = chunk * 8 + (lane >> 3);
      int vcb = ((lane & 7) * 16) ^ ((drow & 7) << 4);
      gload_lds16(vgbase + (long long)drow * 2048 + kv0 + (vcb >> 1),
                  &Vlds[bufi][chunk * 512 + lane * 8]);
    }
  };

  stage(0);
  for (int j = 0; j <= jmax; ++j) {
    __syncthreads();
    if (j < jmax) stage(j + 1);
    const u16* Kb = Klds[j & 1];
    const u16* Vb = Vlds[j & 1];
    int kv0 = j * 64;
    bool skip = (kv0 > wrow0 + 15);
    if (!skip) {
      bool full = (kv0 + 63 <= wrow0);
      facc s[4];
#pragma unroll
      for (int nb = 0; nb < 4; ++nb) {
        s[nb] = zf;
#pragma unroll
        for (int ks = 0; ks < 8; ++ks) {
          int row = nb * 16 + l15;
          bfrag kb = *(const bfrag*)&Kb[row * 256 +
              (((ks * 64 + lg * 16) ^ ((row & 7) << 4)) >> 1)];
          s[nb] = __builtin_amdgcn_mfma_f32_16x16x32_bf16(qf[ks], kb, s[nb], 0, 0, 0);
        }
      }
      float pmax[4] = {-1e30f, -1e30f, -1e30f, -1e30f};
#pragma unroll
      for (int nb = 0; nb < 4; ++nb) {
        int col = kv0 + nb * 16 + l15;
#pragma unroll
        for (int i = 0; i < 4; ++i) {
          float vsc = s[nb][i] * 0.0625f;
          int rowa = wrow0 + lg * 4 + i;
          if (!full && col > rowa) vsc = -1e30f;
          s[nb][i] = vsc;
          pmax[i] = fmaxf(pmax[i], vsc);
        }
      }
#pragma unroll
      for (int i = 0; i < 4; ++i) {
        pmax[i] = fmaxf(pmax[i], __shfl_xor(pmax[i], 1));
        pmax[i] = fmaxf(pmax[i], __shfl_xor(pmax[i], 2));
        pmax[i] = fmaxf(pmax[i], __shfl_xor(pmax[i], 4));
        pmax[i] = fmaxf(pmax[i], __shfl_xor(pmax[i], 8));
      }
      float corr[4], rsum[4];
#pragma unroll
      for (int i = 0; i < 4; ++i) {
        float mn = fmaxf(mrow[i], pmax[i]);
        corr[i] = __expf(mrow[i] - mn);
        mrow[i] = mn;
        rsum[i] = 0.f;
      }
#pragma unroll
      for (int nb = 0; nb < 4; ++nb)
#pragma unroll
        for (int i = 0; i < 4; ++i) {
          float p = __expf(s[nb][i] - mrow[i]);
          s[nb][i] = p;
          rsum[i] += p;
        }
#pragma unroll
      for (int i = 0; i < 4; ++i) {
        rsum[i] += __shfl_xor(rsum[i], 1);
        rsum[i] += __shfl_xor(rsum[i], 2);
        rsum[i] += __shfl_xor(rsum[i], 4);
        rsum[i] += __shfl_xor(rsum[i], 8);
        lrow[i] = lrow[i] * corr[i] + rsum[i];
      }
#pragma unroll
      for (int nb = 0; nb < 16; ++nb)
#pragma unroll
        for (int i = 0; i < 4; ++i) O[nb][i] *= corr[i];
      u16* Pw = (u16*)Plds[wid];
#pragma unroll
      for (int nb = 0; nb < 4; ++nb)
#pragma unroll
        for (int i = 0; i < 4; ++i) {
          int row = lg * 4 + i;
          Pw[(row * 128 + ((nb * 32 + l15 * 2) ^ ((row & 7) << 4))) >> 1] =
              f2bf(s[nb][i]);
        }
      bfrag pa[2];
#pragma unroll
      for (int ksv = 0; ksv < 2; ++ksv)
        pa[ksv] = *(const bfrag*)&Pw[l15 * 64 +
            (((ksv * 64 + lg * 16) ^ ((l15 & 7) << 4)) >> 1)];
#pragma unroll
      for (int nb = 0; nb < 16; ++nb) {
        int d = nb * 16 + l15;
#pragma unroll
        for (int ksv = 0; ksv < 2; ++ksv) {
          bfrag vb = *(const bfrag*)&Vb[d * 64 +
              (((ksv * 64 + lg * 16) ^ ((d & 7) << 4)) >> 1)];
          O[nb] = __builtin_amdgcn_mfma_f32_16x16x32_bf16(pa[ksv], vb, O[nb], 0, 0, 0);
        }
      }
    }
  }
  float rinv[4];
#pragma unroll
  for (int i = 0; i < 4; ++i) rinv[i] = 1.f / lrow[i];
  u16* orow = ocat + (long long)(b * T_ + wrow0) * 1024 + h * 256;
#pragma unroll
  for (int nb = 0; nb < 16; ++nb)
#pragma unroll
    for (int i = 0; i < 4; ++i) {
      int row = lg * 4 + i;
      orow[(long long)row * 1024 + nb * 16 + l15] = f2bf(O[nb][i] * rinv[i]);
    }
}

// ---------------------------------------------------------------- GEMM (NT), 2-phase dbuf
template <int BM, int BN, int LDOUT, int FLAGS, int SPLITK, int SWAP>
__global__ __launch_bounds__(256) void gemm_nt(
    const u16* __restrict__ A, int lda,
    const u16* __restrict__ B, int ldb,
    int K, void* outp, const float* __restrict__ bias) {
  constexpr int MR = BM / 32, NR = BN / 32;
  __shared__ u16 As[2][BM * 32];
  __shared__ u16 Bs[2][BN * 32];
  int gx = SWAP ? blockIdx.y : blockIdx.x;
  int gy = SWAP ? blockIdx.x : blockIdx.y;
  int z = blockIdx.z;
  const u16* Ab = A + (long long)gy * BM * lda + (SPLITK ? z * 256 : 0);
  const u16* Bb = B + (long long)gx * BN * ldb + (SPLITK ? z * 256 : 0);
  float* outf = (float*)outp + (SPLITK ? (long long)z * 1048576 : 0);
  u16* outh = (u16*)outp + (SPLITK ? (long long)z * 1048576 : 0);
  int tid = threadIdx.x;
  int lane = tid & 63, wid = tid >> 6;
  int wr = (wid >> 1) * (BM / 2), wc = (wid & 1) * (BN / 2);
  int srow = tid >> 2, scol = (tid & 3) * 8;

  auto stage = [&](int t, int bufi) {
    int k0 = t * 32;
#pragma unroll
    for (int i = 0; i < BM / 64; ++i)
      gload_lds16(Ab + (long long)(srow + i * 64) * lda + k0 + scol,
                  &As[bufi][(srow + i * 64) * 32 + scol]);
#pragma unroll
    for (int i = 0; i < BN / 64; ++i)
      gload_lds16(Bb + (long long)(srow + i * 64) * ldb + k0 + scol,
                  &Bs[bufi][(srow + i * 64) * 32 + scol]);
  };

  facc acc[MR][NR];
  facc zf = {0.f, 0.f, 0.f, 0.f};
#pragma unroll
  for (int m = 0; m < MR; ++m)
#pragma unroll
    for (int n = 0; n < NR; ++n) acc[m][n] = zf;

  int nt = K >> 5;
  stage(0, 0);
  __syncthreads();
  for (int t = 0; t < nt; ++t) {
    int cur = t & 1;
    if (t + 1 < nt) stage(t + 1, cur ^ 1);
    int kk = (lane >> 4) * 8;
    int ar = wr + (lane & 15);
    int br = wc + (lane & 15);
    bfrag af[MR], bfv[NR];
#pragma unroll
    for (int m = 0; m < MR; ++m) af[m] = *(const bfrag*)&As[cur][(ar + m * 16) * 32 + kk];
#pragma unroll
    for (int n = 0; n < NR; ++n) bfv[n] = *(const bfrag*)&Bs[cur][(br + n * 16) * 32 + kk];
#pragma unroll
    for (int m = 0; m < MR; ++m)
#pragma unroll
      for (int n = 0; n < NR; ++n)
        acc[m][n] = __builtin_amdgcn_mfma_f32_16x16x32_bf16(af[m], bfv[n], acc[m][n], 0, 0, 0);
    __syncthreads();
  }

  int rg = (lane >> 4) * 4;
  int cl = lane & 15;
  int rbase = gy * BM + wr + rg;
  int cbase = gx * BN + wc + cl;
#pragma unroll
  for (int m = 0; m < MR; ++m) {
#pragma unroll
    for (int n = 0; n < NR; ++n) {
      int c_abs = cbase + n * 16;
      float bvv = (FLAGS & FLAG_BIAS) ? bias[c_abs] : 0.f;
#pragma unroll
      for (int i = 0; i < 4; ++i) {
        int r = rbase + m * 16 + i;
        float val = acc[m][n][i] + bvv;
        if (FLAGS & FLAG_RELU) val = fmaxf(val, 0.f);
        int oi = r * LDOUT + c_abs;       // int32, LDOUT compile-time
        if (FLAGS & FLAG_BF16) outh[oi] = f2bf(val);
        else if (FLAGS & FLAG_NT) __builtin_nontemporal_store(val, &outf[oi]);
        else outf[oi] = val;
      }
    }
  }
}

// ---------------------------------------------------------------- launch
extern "C" void kernel_launch(void* const* d_in, const int* in_sizes, int n_in,
                              void* d_out, int out_size, void* d_ws, size_t ws_size,
                              hipStream_t stream) {
  (void)in_sizes; (void)n_in; (void)out_size; (void)ws_size;
  const int*   tokens = (const int*)d_in[0];
  const float* embed  = (const float*)d_in[1];
  const float* pos    = (const float*)d_in[2];
  const float* ln1_g  = (const float*)d_in[3];
  const float* ln1_b  = (const float*)d_in[4];
  const float* wq     = (const float*)d_in[5];
  const float* wk     = (const float*)d_in[6];
  const float* wv     = (const float*)d_in[7];
  const float* wo     = (const float*)d_in[8];
  const float* wo_b   = (const float*)d_in[9];
  const float* ln2_g  = (const float*)d_in[10];
  const float* ln2_b  = (const float*)d_in[11];
  const float* w1     = (const float*)d_in[12];
  const float* b1     = (const float*)d_in[13];
  const float* w2     = (const float*)d_in[14];
  const float* b2     = (const float*)d_in[15];
  const float* lnf_g  = (const float*)d_in[16];
  const float* lnf_b  = (const float*)d_in[17];
  const float* wf     = (const float*)d_in[18];
  const float* bf     = (const float*)d_in[19];
  float* out = (float*)d_out;

  char* ws = (char*)d_ws;
  size_t off = 0;
  auto alloc = [&](size_t bytes) -> char* {
    char* p = ws + off;
    off += (bytes + 255) & ~(size_t)255;
    return p;
  };
  const long long NR = (long long)B_ * T_;
  u16* xn    = (u16*)alloc(NR * C_ * 2);           // single bf16 residual stream
  u16* qkv   = (u16*)alloc(NR * 3072LL * 2);
  u16* vt    = (u16*)alloc((long long)B_ * H_ * C_ * T_ * 2);
  u16* ocat  = (u16*)alloc(NR * (long long)(H_ * C_) * 2);
  u16* hdn   = (u16*)alloc(NR * (long long)FF * 2);
  u16* pbuf  = (u16*)alloc(4LL * NR * C_ * 2);     // split-K partials bf16
  u16* wqkvT = (u16*)alloc((long long)L_ * 3 * H_ * C_ * C_ * 2);
  u16* woT   = (u16*)alloc((long long)L_ * C_ * (H_ * C_) * 2);
  u16* w1T   = (u16*)alloc((long long)L_ * FF * C_ * 2);
  u16* w2T   = (u16*)alloc((long long)L_ * C_ * FF * 2);
  u16* wfT   = (u16*)alloc((long long)V_ * C_ * 2);

  dim3 tb(256);

  transpose_all<<<dim3(14144), tb, 0, stream>>>(wq, wk, wv, wo, w1, w2, wf,
                                                wqkvT, woT, w1T, w2T, wfT);
  embed_ln<<<dim3(1024), tb, 0, stream>>>(tokens, embed, pos, xn, ln1_g, ln1_b);

  for (int l = 0; l < L_; ++l) {
    // QKV: [4096,256]@[3072,256]^T -> qkv [4096][3072]; 128x128 tile, 768 blocks (~3/CU)
    gemm_nt<128, 128, 3072, FLAG_BF16, 0, 0><<<dim3(24, 32, 1), tb, 0, stream>>>(
        xn, C_, wqkvT + (long long)l * 3 * 1024 * 256, C_, C_, qkv, nullptr);
    transpose_v<<<dim3(64, 8, 8), tb, 0, stream>>>(qkv, vt);
    flash_k<<<dim3(256), tb, 0, stream>>>(qkv, vt, ocat);
    // WO: split-K x4 -> pbuf bf16
    gemm_nt<64, 64, 256, FLAG_BF16, 1, 0><<<dim3(4, 64, 4), tb, 0, stream>>>(
        ocat, H_ * C_, woT + (long long)l * C_ * H_ * C_, H_ * C_, C_, pbuf, nullptr);
    reduce_ln<<<dim3(1024), tb, 0, stream>>>(pbuf, xn, wo_b + l * C_,
                                             ln2_g + l * C_, ln2_b + l * C_);
    // MLP1
    gemm_nt<64, 64, 1024, FLAG_BIAS | FLAG_RELU | FLAG_BF16, 0, 0>
        <<<dim3(16, 64, 1), tb, 0, stream>>>(
        xn, C_, w1T + (long long)l * FF * C_, C_, C_, hdn, b1 + l * FF);
    // MLP2: split-K x4 -> pbuf bf16
    gemm_nt<64, 64, 256, FLAG_BF16, 1, 0><<<dim3(4, 64, 4), tb, 0, stream>>>(
        hdn, FF, w2T + (long long)l * C_ * FF, FF, C_, pbuf, nullptr);
    const float* ng = (l < 3) ? (ln1_g + (l + 1) * C_) : lnf_g;
    const float* nb = (l < 3) ? (ln1_b + (l + 1) * C_) : lnf_b;
    reduce_ln<<<dim3(1024), tb, 0, stream>>>(pbuf, xn, b2 + l * C_, ng, nb);
  }
  // logits = xn @ wf + bf  (fp32, [4096][32000], nontemporal stores)
  gemm_nt<128, 128, 32000, FLAG_BIAS | FLAG_NT, 0, 1><<<dim3(32, 250, 1), tb, 0, stream>>>(
      xn, C_, wfT, C_, C_, out, bf);
}

// Round 15
// 777.460 us; speedup vs baseline: 1.4669x; 1.0063x over previous
//
#include <hip/hip_runtime.h>
#include <stdint.h>

#define B_ 2
#define T_ 2048
#define C_ 256
#define H_ 4
#define L_ 4
#define FF 1024
#define V_ 32000

typedef short bfrag __attribute__((ext_vector_type(8)));   // 8 x bf16 (MFMA A/B operand)
typedef float facc  __attribute__((ext_vector_type(4)));   // MFMA C/D
typedef short s4v   __attribute__((ext_vector_type(4)));
typedef short s8v   __attribute__((ext_vector_type(8)));
typedef unsigned short u16;

#define FLAG_BIAS 1
#define FLAG_RELU 4
#define FLAG_BF16 8
#define FLAG_NT   16

__device__ __forceinline__ u16 f2bf(float f) {
  uint32_t x = __float_as_uint(f);
  return (u16)((x + 0x7fffu + ((x >> 16) & 1u)) >> 16);
}
__device__ __forceinline__ float bf2f(u16 u) {
  return __uint_as_float(((uint32_t)u) << 16);
}

__device__ __forceinline__ void gload_lds16(const void* g, void* l) {
  __builtin_amdgcn_global_load_lds(
      (const __attribute__((address_space(1))) uint32_t*)g,
      (__attribute__((address_space(3))) uint32_t*)l, 16, 0, 0);
}

// ---------------------------------------------------------------- all weight transposes
__global__ __launch_bounds__(256) void transpose_all(
    const float* __restrict__ wq, const float* __restrict__ wk,
    const float* __restrict__ wv, const float* __restrict__ wo,
    const float* __restrict__ w1, const float* __restrict__ w2,
    const float* __restrict__ wf,
    u16* __restrict__ wqkvT, u16* __restrict__ woT, u16* __restrict__ w1T,
    u16* __restrict__ w2T, u16* __restrict__ wfT) {
  int bid = blockIdx.x;
  const float* in;
  u16* out;
  int R, Cc, cx, ry;
  long long zi, zo;
  if (bid < 3072) {              // wq/wk/wv: [16][256][256] -> wqkvT [L][3][1024][256]
    int job = bid >> 10, w = bid & 1023;
    int z = w >> 6, t = w & 63;
    cx = t & 7; ry = t >> 3; R = 256; Cc = 256;
    in = (job == 0 ? wq : job == 1 ? wk : wv);
    zi = (long long)z * 65536;
    zo = (long long)(z >> 2) * 786432 + (long long)(z & 3) * 65536
       + (long long)job * 262144;
    out = wqkvT;
  } else if (bid < 4096) {       // wo: [4][1024][256] -> [4][256][1024]
    int w = bid - 3072; int z = w >> 8, t = w & 255;
    cx = t & 7; ry = t >> 3; R = 1024; Cc = 256;
    in = wo; zi = (long long)z * 262144; zo = zi; out = woT;
  } else if (bid < 5120) {       // w1: [4][256][1024] -> [4][1024][256]
    int w = bid - 4096; int z = w >> 8, t = w & 255;
    cx = t & 31; ry = t >> 5; R = 256; Cc = 1024;
    in = w1; zi = (long long)z * 262144; zo = zi; out = w1T;
  } else if (bid < 6144) {       // w2: [4][1024][256] -> [4][256][1024]
    int w = bid - 5120; int z = w >> 8, t = w & 255;
    cx = t & 7; ry = t >> 3; R = 1024; Cc = 256;
    in = w2; zi = (long long)z * 262144; zo = zi; out = w2T;
  } else {                       // wf: [256][32000] -> [32000][256]
    int t = bid - 6144; cx = t % 1000; ry = t / 1000;
    R = 256; Cc = 32000; in = wf; zi = 0; zo = 0; out = wfT;
  }
  __shared__ float tile[32][33];
  int c0 = cx * 32, r0 = ry * 32;
  int tx = threadIdx.x & 31, ty = threadIdx.x >> 5;
#pragma unroll
  for (int i = ty; i < 32; i += 8)
    tile[i][tx] = in[zi + (long long)(r0 + i) * Cc + (c0 + tx)];
  __syncthreads();
#pragma unroll
  for (int i = ty; i < 32; i += 8)
    out[zo + (long long)(c0 + i) * R + (r0 + tx)] = f2bf(tile[tx][i]);
}

// ---------------------------------------------------------------- V transpose (u16)
__global__ __launch_bounds__(256) void transpose_v(const u16* __restrict__ qkv,
                                                   u16* __restrict__ vt) {
  __shared__ u16 tile[32][33];
  int z = blockIdx.z, b = z >> 2, h = z & 3;
  const u16* in = qkv + (long long)b * T_ * 3072 + 2048 + h * 256;
  int t0 = blockIdx.x * 32, d0 = blockIdx.y * 32;
  int tx = threadIdx.x & 31, ty = threadIdx.x >> 5;
#pragma unroll
  for (int i = ty; i < 32; i += 8)
    tile[i][tx] = in[(long long)(t0 + i) * 3072 + (d0 + tx)];
  __syncthreads();
#pragma unroll
  for (int i = ty; i < 32; i += 8)
    vt[((long long)z * 256 + d0 + i) * T_ + (t0 + tx)] = tile[tx][i];
}

// ---------------------------------------------------------------- embed + LN1(l=0) fused
__global__ __launch_bounds__(256) void embed_ln(const int* __restrict__ tok,
                                                const float* __restrict__ emb,
                                                const float* __restrict__ pos,
                                                u16* __restrict__ xn,
                                                const float* __restrict__ g,
                                                const float* __restrict__ b) {
  int wid = threadIdx.x >> 6, lane = threadIdx.x & 63;
  int row = blockIdx.x * 4 + wid;
  int t = row & (T_ - 1);
  float4 ev = ((const float4*)(emb + (long long)tok[row] * C_))[lane];
  float4 pv = ((const float4*)(pos + (long long)t * C_))[lane];
  float4 v;
  v.x = ev.x + pv.x; v.y = ev.y + pv.y; v.z = ev.z + pv.z; v.w = ev.w + pv.w;
  float s = v.x + v.y + v.z + v.w;
#pragma unroll
  for (int o = 32; o > 0; o >>= 1) s += __shfl_xor(s, o);
  float mean = s * (1.f / 256.f);
  float d0 = v.x - mean, d1 = v.y - mean, d2 = v.z - mean, d3 = v.w - mean;
  float q2 = d0 * d0 + d1 * d1 + d2 * d2 + d3 * d3;
#pragma unroll
  for (int o = 32; o > 0; o >>= 1) q2 += __shfl_xor(q2, o);
  float rstd = rsqrtf(q2 * (1.f / 256.f) + 1e-5f);
  float4 gv = ((const float4*)g)[lane];
  float4 bv = ((const float4*)b)[lane];
  u16 tmp[4] = {f2bf(d0 * rstd * gv.x + bv.x), f2bf(d1 * rstd * gv.y + bv.y),
                f2bf(d2 * rstd * gv.z + bv.z), f2bf(d3 * rstd * gv.w + bv.w)};
  *(s4v*)&xn[(long long)row * C_ + lane * 4] = *(const s4v*)tmp;
}

// ---------------------------------------------------------------- split-K(2) reduce (bf16 partials) + bias + residual + LN
__global__ __launch_bounds__(256) void reduce_ln(const u16* __restrict__ pbuf,
                                                 u16* __restrict__ xn,
                                                 const float* __restrict__ bias,
                                                 const float* __restrict__ g,
                                                 const float* __restrict__ b) {
  int wid = threadIdx.x >> 6, lane = threadIdx.x & 63;
  long long row = (long long)blockIdx.x * 4 + wid;
  const u16* p = pbuf + row * C_ + lane * 4;
  const int SL = 1048576;
  s4v rv = *(const s4v*)&xn[row * C_ + lane * 4];
  float4 bi = ((const float4*)bias)[lane];
  float4 v;
  v.x = bf2f((u16)rv[0]) + bi.x;
  v.y = bf2f((u16)rv[1]) + bi.y;
  v.z = bf2f((u16)rv[2]) + bi.z;
  v.w = bf2f((u16)rv[3]) + bi.w;
#pragma unroll
  for (int sI = 0; sI < 2; ++sI) {
    s4v pv = *(const s4v*)(p + sI * SL);
    v.x += bf2f((u16)pv[0]);
    v.y += bf2f((u16)pv[1]);
    v.z += bf2f((u16)pv[2]);
    v.w += bf2f((u16)pv[3]);
  }
  float s = v.x + v.y + v.z + v.w;
#pragma unroll
  for (int o = 32; o > 0; o >>= 1) s += __shfl_xor(s, o);
  float mean = s * (1.f / 256.f);
  float d0 = v.x - mean, d1 = v.y - mean, d2 = v.z - mean, d3 = v.w - mean;
  float q2 = d0 * d0 + d1 * d1 + d2 * d2 + d3 * d3;
#pragma unroll
  for (int o = 32; o > 0; o >>= 1) q2 += __shfl_xor(q2, o);
  float rstd = rsqrtf(q2 * (1.f / 256.f) + 1e-5f);
  float4 gv = ((const float4*)g)[lane];
  float4 bv = ((const float4*)b)[lane];
  u16 tmp[4] = {f2bf(d0 * rstd * gv.x + bv.x), f2bf(d1 * rstd * gv.y + bv.y),
                f2bf(d2 * rstd * gv.z + bv.z), f2bf(d3 * rstd * gv.w + bv.w)};
  *(s4v*)&xn[row * C_ + lane * 4] = *(const s4v*)tmp;
}

// ---------------------------------------------------------------- flash attention (R11 4-wave, z-affinity)
__global__ __launch_bounds__(256, 1) void flash_k(const u16* __restrict__ qkv,
                                                  const u16* __restrict__ vt,
                                                  u16* __restrict__ ocat) {
  __shared__ u16 Klds[2][64 * 256];
  __shared__ u16 Vlds[2][256 * 64];
  __shared__ u16 Plds[4][1024];
  int bid = blockIdx.x;
  int z = bid & 7, ib = bid >> 3;
  int b = z >> 2, h = z & 3;
  int lo0 = ib * 32, hi0 = 2016 - ib * 32;
  int tid = threadIdx.x, lane = tid & 63, wid = tid >> 6;
  int l15 = lane & 15, lg = lane >> 4;
  int wrow0 = (wid < 2) ? (lo0 + wid * 16) : (hi0 + (wid - 2) * 16);
  int jmax = (hi0 + 31) >> 6;

  bfrag qf[8];
  {
    const u16* qrow = qkv + (long long)(b * T_ + wrow0 + l15) * 3072 + h * 256 + lg * 8;
#pragma unroll
    for (int ks = 0; ks < 8; ++ks) qf[ks] = *(const bfrag*)(qrow + ks * 32);
  }
  facc zf = {0.f, 0.f, 0.f, 0.f};
  facc O[16];
#pragma unroll
  for (int nb = 0; nb < 16; ++nb) O[nb] = zf;
  float mrow[4] = {-1e30f, -1e30f, -1e30f, -1e30f};
  float lrow[4] = {0.f, 0.f, 0.f, 0.f};

  const u16* kgbase = qkv + (long long)(b * T_) * 3072 + 1024 + h * 256;
  const u16* vgbase = vt + (long long)z * 256 * 2048;

  auto stage = [&](int j) {
    int kv0 = j * 64;
    int bufi = j & 1;
#pragma unroll
    for (int c = 0; c < 8; ++c) {
      int chunk = wid * 8 + c;
      int krow = chunk * 2 + (lane >> 5);
      int kcb = ((lane & 31) * 16) ^ ((krow & 7) << 4);
      gload_lds16(kgbase + (long long)(kv0 + krow) * 3072 + (kcb >> 1),
                  &Klds[bufi][chunk * 512 + lane * 8]);
      int drow = chunk * 8 + (lane >> 3);
      int vcb = ((lane & 7) * 16) ^ ((drow & 7) << 4);
      gload_lds16(vgbase + (long long)drow * 2048 + kv0 + (vcb >> 1),
                  &Vlds[bufi][chunk * 512 + lane * 8]);
    }
  };

  stage(0);
  for (int j = 0; j <= jmax; ++j) {
    __syncthreads();
    if (j < jmax) stage(j + 1);
    const u16* Kb = Klds[j & 1];
    const u16* Vb = Vlds[j & 1];
    int kv0 = j * 64;
    bool skip = (kv0 > wrow0 + 15);
    if (!skip) {
      bool full = (kv0 + 63 <= wrow0);
      facc s[4];
#pragma unroll
      for (int nb = 0; nb < 4; ++nb) {
        s[nb] = zf;
#pragma unroll
        for (int ks = 0; ks < 8; ++ks) {
          int row = nb * 16 + l15;
          bfrag kb = *(const bfrag*)&Kb[row * 256 +
              (((ks * 64 + lg * 16) ^ ((row & 7) << 4)) >> 1)];
          s[nb] = __builtin_amdgcn_mfma_f32_16x16x32_bf16(qf[ks], kb, s[nb], 0, 0, 0);
        }
      }
      float pmax[4] = {-1e30f, -1e30f, -1e30f, -1e30f};
#pragma unroll
      for (int nb = 0; nb < 4; ++nb) {
        int col = kv0 + nb * 16 + l15;
#pragma unroll
        for (int i = 0; i < 4; ++i) {
          float vsc = s[nb][i] * 0.0625f;
          int rowa = wrow0 + lg * 4 + i;
          if (!full && col > rowa) vsc = -1e30f;
          s[nb][i] = vsc;
          pmax[i] = fmaxf(pmax[i], vsc);
        }
      }
#pragma unroll
      for (int i = 0; i < 4; ++i) {
        pmax[i] = fmaxf(pmax[i], __shfl_xor(pmax[i], 1));
        pmax[i] = fmaxf(pmax[i], __shfl_xor(pmax[i], 2));
        pmax[i] = fmaxf(pmax[i], __shfl_xor(pmax[i], 4));
        pmax[i] = fmaxf(pmax[i], __shfl_xor(pmax[i], 8));
      }
      float corr[4], rsum[4];
#pragma unroll
      for (int i = 0; i < 4; ++i) {
        float mn = fmaxf(mrow[i], pmax[i]);
        corr[i] = __expf(mrow[i] - mn);
        mrow[i] = mn;
        rsum[i] = 0.f;
      }
#pragma unroll
      for (int nb = 0; nb < 4; ++nb)
#pragma unroll
        for (int i = 0; i < 4; ++i) {
          float p = __expf(s[nb][i] - mrow[i]);
          s[nb][i] = p;
          rsum[i] += p;
        }
#pragma unroll
      for (int i = 0; i < 4; ++i) {
        rsum[i] += __shfl_xor(rsum[i], 1);
        rsum[i] += __shfl_xor(rsum[i], 2);
        rsum[i] += __shfl_xor(rsum[i], 4);
        rsum[i] += __shfl_xor(rsum[i], 8);
        lrow[i] = lrow[i] * corr[i] + rsum[i];
      }
#pragma unroll
      for (int nb = 0; nb < 16; ++nb)
#pragma unroll
        for (int i = 0; i < 4; ++i) O[nb][i] *= corr[i];
      u16* Pw = (u16*)Plds[wid];
#pragma unroll
      for (int nb = 0; nb < 4; ++nb)
#pragma unroll
        for (int i = 0; i < 4; ++i) {
          int row = lg * 4 + i;
          Pw[(row * 128 + ((nb * 32 + l15 * 2) ^ ((row & 7) << 4))) >> 1] =
              f2bf(s[nb][i]);
        }
      bfrag pa[2];
#pragma unroll
      for (int ksv = 0; ksv < 2; ++ksv)
        pa[ksv] = *(const bfrag*)&Pw[l15 * 64 +
            (((ksv * 64 + lg * 16) ^ ((l15 & 7) << 4)) >> 1)];
#pragma unroll
      for (int nb = 0; nb < 16; ++nb) {
        int d = nb * 16 + l15;
#pragma unroll
        for (int ksv = 0; ksv < 2; ++ksv) {
          bfrag vb = *(const bfrag*)&Vb[d * 64 +
              (((ksv * 64 + lg * 16) ^ ((d & 7) << 4)) >> 1)];
          O[nb] = __builtin_amdgcn_mfma_f32_16x16x32_bf16(pa[ksv], vb, O[nb], 0, 0, 0);
        }
      }
    }
  }
  float rinv[4];
#pragma unroll
  for (int i = 0; i < 4; ++i) rinv[i] = 1.f / lrow[i];
  u16* orow = ocat + (long long)(b * T_ + wrow0) * 1024 + h * 256;
#pragma unroll
  for (int nb = 0; nb < 16; ++nb)
#pragma unroll
    for (int i = 0; i < 4; ++i) {
      int row = lg * 4 + i;
      orow[(long long)row * 1024 + nb * 16 + l15] = f2bf(O[nb][i] * rinv[i]);
    }
}

// ---------------------------------------------------------------- GEMM (NT), 2-phase dbuf
// SPLITK: z selects 512-elem K-chunk of A/B and a 1M-elem out slice (2 slices).
template <int BM, int BN, int LDOUT, int FLAGS, int SPLITK, int SWAP>
__global__ __launch_bounds__(256) void gemm_nt(
    const u16* __restrict__ A, int lda,
    const u16* __restrict__ B, int ldb,
    int K, void* outp, const float* __restrict__ bias) {
  constexpr int MR = BM / 32, NR = BN / 32;
  __shared__ u16 As[2][BM * 32];
  __shared__ u16 Bs[2][BN * 32];
  int gx = SWAP ? blockIdx.y : blockIdx.x;
  int gy = SWAP ? blockIdx.x : blockIdx.y;
  int z = blockIdx.z;
  const u16* Ab = A + (long long)gy * BM * lda + (SPLITK ? z * 512 : 0);
  const u16* Bb = B + (long long)gx * BN * ldb + (SPLITK ? z * 512 : 0);
  float* outf = (float*)outp + (SPLITK ? (long long)z * 1048576 : 0);
  u16* outh = (u16*)outp + (SPLITK ? (long long)z * 1048576 : 0);
  int tid = threadIdx.x;
  int lane = tid & 63, wid = tid >> 6;
  int wr = (wid >> 1) * (BM / 2), wc = (wid & 1) * (BN / 2);
  int srow = tid >> 2, scol = (tid & 3) * 8;

  auto stage = [&](int t, int bufi) {
    int k0 = t * 32;
#pragma unroll
    for (int i = 0; i < BM / 64; ++i)
      gload_lds16(Ab + (long long)(srow + i * 64) * lda + k0 + scol,
                  &As[bufi][(srow + i * 64) * 32 + scol]);
#pragma unroll
    for (int i = 0; i < BN / 64; ++i)
      gload_lds16(Bb + (long long)(srow + i * 64) * ldb + k0 + scol,
                  &Bs[bufi][(srow + i * 64) * 32 + scol]);
  };

  facc acc[MR][NR];
  facc zf = {0.f, 0.f, 0.f, 0.f};
#pragma unroll
  for (int m = 0; m < MR; ++m)
#pragma unroll
    for (int n = 0; n < NR; ++n) acc[m][n] = zf;

  int nt = K >> 5;
  stage(0, 0);
  __syncthreads();
  for (int t = 0; t < nt; ++t) {
    int cur = t & 1;
    if (t + 1 < nt) stage(t + 1, cur ^ 1);
    int kk = (lane >> 4) * 8;
    int ar = wr + (lane & 15);
    int br = wc + (lane & 15);
    bfrag af[MR], bfv[NR];
#pragma unroll
    for (int m = 0; m < MR; ++m) af[m] = *(const bfrag*)&As[cur][(ar + m * 16) * 32 + kk];
#pragma unroll
    for (int n = 0; n < NR; ++n) bfv[n] = *(const bfrag*)&Bs[cur][(br + n * 16) * 32 + kk];
#pragma unroll
    for (int m = 0; m < MR; ++m)
#pragma unroll
      for (int n = 0; n < NR; ++n)
        acc[m][n] = __builtin_amdgcn_mfma_f32_16x16x32_bf16(af[m], bfv[n], acc[m][n], 0, 0, 0);
    __syncthreads();
  }

  int rg = (lane >> 4) * 4;
  int cl = lane & 15;
  int rbase = gy * BM + wr + rg;
  int cbase = gx * BN + wc + cl;
#pragma unroll
  for (int m = 0; m < MR; ++m) {
#pragma unroll
    for (int n = 0; n < NR; ++n) {
      int c_abs = cbase + n * 16;
      float bvv = (FLAGS & FLAG_BIAS) ? bias[c_abs] : 0.f;
#pragma unroll
      for (int i = 0; i < 4; ++i) {
        int r = rbase + m * 16 + i;
        float val = acc[m][n][i] + bvv;
        if (FLAGS & FLAG_RELU) val = fmaxf(val, 0.f);
        int oi = r * LDOUT + c_abs;       // int32, LDOUT compile-time
        if (FLAGS & FLAG_BF16) outh[oi] = f2bf(val);
        else if (FLAGS & FLAG_NT) __builtin_nontemporal_store(val, &outf[oi]);
        else outf[oi] = val;
      }
    }
  }
}

// ---------------------------------------------------------------- launch
extern "C" void kernel_launch(void* const* d_in, const int* in_sizes, int n_in,
                              void* d_out, int out_size, void* d_ws, size_t ws_size,
                              hipStream_t stream) {
  (void)in_sizes; (void)n_in; (void)out_size; (void)ws_size;
  const int*   tokens = (const int*)d_in[0];
  const float* embed  = (const float*)d_in[1];
  const float* pos    = (const float*)d_in[2];
  const float* ln1_g  = (const float*)d_in[3];
  const float* ln1_b  = (const float*)d_in[4];
  const float* wq     = (const float*)d_in[5];
  const float* wk     = (const float*)d_in[6];
  const float* wv     = (const float*)d_in[7];
  const float* wo     = (const float*)d_in[8];
  const float* wo_b   = (const float*)d_in[9];
  const float* ln2_g  = (const float*)d_in[10];
  const float* ln2_b  = (const float*)d_in[11];
  const float* w1     = (const float*)d_in[12];
  const float* b1     = (const float*)d_in[13];
  const float* w2     = (const float*)d_in[14];
  const float* b2     = (const float*)d_in[15];
  const float* lnf_g  = (const float*)d_in[16];
  const float* lnf_b  = (const float*)d_in[17];
  const float* wf     = (const float*)d_in[18];
  const float* bf     = (const float*)d_in[19];
  float* out = (float*)d_out;

  char* ws = (char*)d_ws;
  size_t off = 0;
  auto alloc = [&](size_t bytes) -> char* {
    char* p = ws + off;
    off += (bytes + 255) & ~(size_t)255;
    return p;
  };
  const long long NR = (long long)B_ * T_;
  u16* xn    = (u16*)alloc(NR * C_ * 2);           // single bf16 residual stream
  u16* qkv   = (u16*)alloc(NR * 3072LL * 2);
  u16* vt    = (u16*)alloc((long long)B_ * H_ * C_ * T_ * 2);
  u16* ocat  = (u16*)alloc(NR * (long long)(H_ * C_) * 2);
  u16* hdn   = (u16*)alloc(NR * (long long)FF * 2);
  u16* pbuf  = (u16*)alloc(2LL * NR * C_ * 2);     // split-K(2) partials bf16
  u16* wqkvT = (u16*)alloc((long long)L_ * 3 * H_ * C_ * C_ * 2);
  u16* woT   = (u16*)alloc((long long)L_ * C_ * (H_ * C_) * 2);
  u16* w1T   = (u16*)alloc((long long)L_ * FF * C_ * 2);
  u16* w2T   = (u16*)alloc((long long)L_ * C_ * FF * 2);
  u16* wfT   = (u16*)alloc((long long)V_ * C_ * 2);

  dim3 tb(256);

  transpose_all<<<dim3(14144), tb, 0, stream>>>(wq, wk, wv, wo, w1, w2, wf,
                                                wqkvT, woT, w1T, w2T, wfT);
  embed_ln<<<dim3(1024), tb, 0, stream>>>(tokens, embed, pos, xn, ln1_g, ln1_b);

  for (int l = 0; l < L_; ++l) {
    // QKV: [4096,256]@[3072,256]^T -> qkv [4096][3072]; 128x128 tile, 768 blocks (~3/CU)
    gemm_nt<128, 128, 3072, FLAG_BF16, 0, 0><<<dim3(24, 32, 1), tb, 0, stream>>>(
        xn, C_, wqkvT + (long long)l * 3 * 1024 * 256, C_, C_, qkv, nullptr);
    transpose_v<<<dim3(64, 8, 8), tb, 0, stream>>>(qkv, vt);
    flash_k<<<dim3(256), tb, 0, stream>>>(qkv, vt, ocat);
    // WO: split-K x2 (K=512/slice) -> pbuf bf16
    gemm_nt<64, 64, 256, FLAG_BF16, 1, 0><<<dim3(4, 64, 2), tb, 0, stream>>>(
        ocat, H_ * C_, woT + (long long)l * C_ * H_ * C_, H_ * C_, 512, pbuf, nullptr);
    reduce_ln<<<dim3(1024), tb, 0, stream>>>(pbuf, xn, wo_b + l * C_,
                                             ln2_g + l * C_, ln2_b + l * C_);
    // MLP1
    gemm_nt<64, 64, 1024, FLAG_BIAS | FLAG_RELU | FLAG_BF16, 0, 0>
        <<<dim3(16, 64, 1), tb, 0, stream>>>(
        xn, C_, w1T + (long long)l * FF * C_, C_, C_, hdn, b1 + l * FF);
    // MLP2: split-K x2 (K=512/slice) -> pbuf bf16
    gemm_nt<64, 64, 256, FLAG_BF16, 1, 0><<<dim3(4, 64, 2), tb, 0, stream>>>(
        hdn, FF, w2T + (long long)l * C_ * FF, FF, 512, pbuf, nullptr);
    const float* ng = (l < 3) ? (ln1_g + (l + 1) * C_) : lnf_g;
    const float* nb = (l < 3) ? (ln1_b + (l + 1) * C_) : lnf_b;
    reduce_ln<<<dim3(1024), tb, 0, stream>>>(pbuf, xn, b2 + l * C_, ng, nb);
  }
  // logits = xn @ wf + bf  (fp32, [4096][32000], nontemporal stores)
  gemm_nt<128, 128, 32000, FLAG_BIAS | FLAG_NT, 0, 1><<<dim3(32, 250, 1), tb, 0, stream>>>(
      xn, C_, wfT, C_, C_, out, bf);
}

// Round 16
// 774.132 us; speedup vs baseline: 1.4732x; 1.0043x over previous
//
#include <hip/hip_runtime.h>
#include <stdint.h>

#define B_ 2
#define T_ 2048
#define C_ 256
#define H_ 4
#define L_ 4
#define FF 1024
#define V_ 32000

typedef short bfrag __attribute__((ext_vector_type(8)));   // 8 x bf16 (MFMA A/B operand)
typedef float facc  __attribute__((ext_vector_type(4)));   // MFMA C/D
typedef short s4v   __attribute__((ext_vector_type(4)));
typedef short s8v   __attribute__((ext_vector_type(8)));
typedef unsigned short u16;

#define FLAG_BIAS 1
#define FLAG_RELU 4
#define FLAG_BF16 8
#define FLAG_NT   16

__device__ __forceinline__ u16 f2bf(float f) {
  uint32_t x = __float_as_uint(f);
  return (u16)((x + 0x7fffu + ((x >> 16) & 1u)) >> 16);
}
__device__ __forceinline__ float bf2f(u16 u) {
  return __uint_as_float(((uint32_t)u) << 16);
}

__device__ __forceinline__ void gload_lds16(const void* g, void* l) {
  __builtin_amdgcn_global_load_lds(
      (const __attribute__((address_space(1))) uint32_t*)g,
      (__attribute__((address_space(3))) uint32_t*)l, 16, 0, 0);
}

// ---------------------------------------------------------------- all weight transposes
__global__ __launch_bounds__(256) void transpose_all(
    const float* __restrict__ wq, const float* __restrict__ wk,
    const float* __restrict__ wv, const float* __restrict__ wo,
    const float* __restrict__ w1, const float* __restrict__ w2,
    const float* __restrict__ wf,
    u16* __restrict__ wqkvT, u16* __restrict__ woT, u16* __restrict__ w1T,
    u16* __restrict__ w2T, u16* __restrict__ wfT) {
  int bid = blockIdx.x;
  const float* in;
  u16* out;
  int R, Cc, cx, ry;
  long long zi, zo;
  if (bid < 3072) {              // wq/wk/wv: [16][256][256] -> wqkvT [L][3][1024][256]
    int job = bid >> 10, w = bid & 1023;
    int z = w >> 6, t = w & 63;
    cx = t & 7; ry = t >> 3; R = 256; Cc = 256;
    in = (job == 0 ? wq : job == 1 ? wk : wv);
    zi = (long long)z * 65536;
    zo = (long long)(z >> 2) * 786432 + (long long)(z & 3) * 65536
       + (long long)job * 262144;
    out = wqkvT;
  } else if (bid < 4096) {       // wo: [4][1024][256] -> [4][256][1024]
    int w = bid - 3072; int z = w >> 8, t = w & 255;
    cx = t & 7; ry = t >> 3; R = 1024; Cc = 256;
    in = wo; zi = (long long)z * 262144; zo = zi; out = woT;
  } else if (bid < 5120) {       // w1: [4][256][1024] -> [4][1024][256]
    int w = bid - 4096; int z = w >> 8, t = w & 255;
    cx = t & 31; ry = t >> 5; R = 256; Cc = 1024;
    in = w1; zi = (long long)z * 262144; zo = zi; out = w1T;
  } else if (bid < 6144) {       // w2: [4][1024][256] -> [4][256][1024]
    int w = bid - 5120; int z = w >> 8, t = w & 255;
    cx = t & 7; ry = t >> 3; R = 1024; Cc = 256;
    in = w2; zi = (long long)z * 262144; zo = zi; out = w2T;
  } else {                       // wf: [256][32000] -> [32000][256]
    int t = bid - 6144; cx = t % 1000; ry = t / 1000;
    R = 256; Cc = 32000; in = wf; zi = 0; zo = 0; out = wfT;
  }
  __shared__ float tile[32][33];
  int c0 = cx * 32, r0 = ry * 32;
  int tx = threadIdx.x & 31, ty = threadIdx.x >> 5;
#pragma unroll
  for (int i = ty; i < 32; i += 8)
    tile[i][tx] = in[zi + (long long)(r0 + i) * Cc + (c0 + tx)];
  __syncthreads();
#pragma unroll
  for (int i = ty; i < 32; i += 8)
    out[zo + (long long)(c0 + i) * R + (r0 + tx)] = f2bf(tile[tx][i]);
}

// ---------------------------------------------------------------- V transpose (u16)
__global__ __launch_bounds__(256) void transpose_v(const u16* __restrict__ qkv,
                                                   u16* __restrict__ vt) {
  __shared__ u16 tile[32][33];
  int z = blockIdx.z, b = z >> 2, h = z & 3;
  const u16* in = qkv + (long long)b * T_ * 3072 + 2048 + h * 256;
  int t0 = blockIdx.x * 32, d0 = blockIdx.y * 32;
  int tx = threadIdx.x & 31, ty = threadIdx.x >> 5;
#pragma unroll
  for (int i = ty; i < 32; i += 8)
    tile[i][tx] = in[(long long)(t0 + i) * 3072 + (d0 + tx)];
  __syncthreads();
#pragma unroll
  for (int i = ty; i < 32; i += 8)
    vt[((long long)z * 256 + d0 + i) * T_ + (t0 + tx)] = tile[tx][i];
}

// ---------------------------------------------------------------- embed + LN1(l=0) fused
__global__ __launch_bounds__(256) void embed_ln(const int* __restrict__ tok,
                                                const float* __restrict__ emb,
                                                const float* __restrict__ pos,
                                                u16* __restrict__ xn,
                                                const float* __restrict__ g,
                                                const float* __restrict__ b) {
  int wid = threadIdx.x >> 6, lane = threadIdx.x & 63;
  int row = blockIdx.x * 4 + wid;
  int t = row & (T_ - 1);
  float4 ev = ((const float4*)(emb + (long long)tok[row] * C_))[lane];
  float4 pv = ((const float4*)(pos + (long long)t * C_))[lane];
  float4 v;
  v.x = ev.x + pv.x; v.y = ev.y + pv.y; v.z = ev.z + pv.z; v.w = ev.w + pv.w;
  float s = v.x + v.y + v.z + v.w;
#pragma unroll
  for (int o = 32; o > 0; o >>= 1) s += __shfl_xor(s, o);
  float mean = s * (1.f / 256.f);
  float d0 = v.x - mean, d1 = v.y - mean, d2 = v.z - mean, d3 = v.w - mean;
  float q2 = d0 * d0 + d1 * d1 + d2 * d2 + d3 * d3;
#pragma unroll
  for (int o = 32; o > 0; o >>= 1) q2 += __shfl_xor(q2, o);
  float rstd = rsqrtf(q2 * (1.f / 256.f) + 1e-5f);
  float4 gv = ((const float4*)g)[lane];
  float4 bv = ((const float4*)b)[lane];
  u16 tmp[4] = {f2bf(d0 * rstd * gv.x + bv.x), f2bf(d1 * rstd * gv.y + bv.y),
                f2bf(d2 * rstd * gv.z + bv.z), f2bf(d3 * rstd * gv.w + bv.w)};
  *(s4v*)&xn[(long long)row * C_ + lane * 4] = *(const s4v*)tmp;
}

// ---------------------------------------------------------------- split-K(2) reduce (bf16 partials) + bias + residual + LN
__global__ __launch_bounds__(256) void reduce_ln(const u16* __restrict__ pbuf,
                                                 u16* __restrict__ xn,
                                                 const float* __restrict__ bias,
                                                 const float* __restrict__ g,
                                                 const float* __restrict__ b) {
  int wid = threadIdx.x >> 6, lane = threadIdx.x & 63;
  long long row = (long long)blockIdx.x * 4 + wid;
  const u16* p = pbuf + row * C_ + lane * 4;
  const int SL = 1048576;
  s4v rv = *(const s4v*)&xn[row * C_ + lane * 4];
  float4 bi = ((const float4*)bias)[lane];
  float4 v;
  v.x = bf2f((u16)rv[0]) + bi.x;
  v.y = bf2f((u16)rv[1]) + bi.y;
  v.z = bf2f((u16)rv[2]) + bi.z;
  v.w = bf2f((u16)rv[3]) + bi.w;
#pragma unroll
  for (int sI = 0; sI < 2; ++sI) {
    s4v pv = *(const s4v*)(p + sI * SL);
    v.x += bf2f((u16)pv[0]);
    v.y += bf2f((u16)pv[1]);
    v.z += bf2f((u16)pv[2]);
    v.w += bf2f((u16)pv[3]);
  }
  float s = v.x + v.y + v.z + v.w;
#pragma unroll
  for (int o = 32; o > 0; o >>= 1) s += __shfl_xor(s, o);
  float mean = s * (1.f / 256.f);
  float d0 = v.x - mean, d1 = v.y - mean, d2 = v.z - mean, d3 = v.w - mean;
  float q2 = d0 * d0 + d1 * d1 + d2 * d2 + d3 * d3;
#pragma unroll
  for (int o = 32; o > 0; o >>= 1) q2 += __shfl_xor(q2, o);
  float rstd = rsqrtf(q2 * (1.f / 256.f) + 1e-5f);
  float4 gv = ((const float4*)g)[lane];
  float4 bv = ((const float4*)b)[lane];
  u16 tmp[4] = {f2bf(d0 * rstd * gv.x + bv.x), f2bf(d1 * rstd * gv.y + bv.y),
                f2bf(d2 * rstd * gv.z + bv.z), f2bf(d3 * rstd * gv.w + bv.w)};
  *(s4v*)&xn[row * C_ + lane * 4] = *(const s4v*)tmp;
}

// ---------------------------------------------------------------- flash attention (R11 4-wave, z-affinity)
__global__ __launch_bounds__(256, 1) void flash_k(const u16* __restrict__ qkv,
                                                  const u16* __restrict__ vt,
                                                  u16* __restrict__ ocat) {
  __shared__ u16 Klds[2][64 * 256];
  __shared__ u16 Vlds[2][256 * 64];
  __shared__ u16 Plds[4][1024];
  int bid = blockIdx.x;
  int z = bid & 7, ib = bid >> 3;
  int b = z >> 2, h = z & 3;
  int lo0 = ib * 32, hi0 = 2016 - ib * 32;
  int tid = threadIdx.x, lane = tid & 63, wid = tid >> 6;
  int l15 = lane & 15, lg = lane >> 4;
  int wrow0 = (wid < 2) ? (lo0 + wid * 16) : (hi0 + (wid - 2) * 16);
  int jmax = (hi0 + 31) >> 6;

  bfrag qf[8];
  {
    const u16* qrow = qkv + (long long)(b * T_ + wrow0 + l15) * 3072 + h * 256 + lg * 8;
#pragma unroll
    for (int ks = 0; ks < 8; ++ks) qf[ks] = *(const bfrag*)(qrow + ks * 32);
  }
  facc zf = {0.f, 0.f, 0.f, 0.f};
  facc O[16];
#pragma unroll
  for (int nb = 0; nb < 16; ++nb) O[nb] = zf;
  float mrow[4] = {-1e30f, -1e30f, -1e30f, -1e30f};
  float lrow[4] = {0.f, 0.f, 0.f, 0.f};

  const u16* kgbase = qkv + (long long)(b * T_) * 3072 + 1024 + h * 256;
  const u16* vgbase = vt + (long long)z * 256 * 2048;

  auto stage = [&](int j) {
    int kv0 = j * 64;
    int bufi = j & 1;
#pragma unroll
    for (int c = 0; c < 8; ++c) {
      int chunk = wid * 8 + c;
      int krow = chunk * 2 + (lane >> 5);
      int kcb = ((lane & 31) * 16) ^ ((krow & 7) << 4);
      gload_lds16(kgbase + (long long)(kv0 + krow) * 3072 + (kcb >> 1),
                  &Klds[bufi][chunk * 512 + lane * 8]);
      int drow = chunk * 8 + (lane >> 3);
      int vcb = ((lane & 7) * 16) ^ ((drow & 7) << 4);
      gload_lds16(vgbase + (long long)drow * 2048 + kv0 + (vcb >> 1),
                  &Vlds[bufi][chunk * 512 + lane * 8]);
    }
  };

  stage(0);
  for (int j = 0; j <= jmax; ++j) {
    __syncthreads();
    if (j < jmax) stage(j + 1);
    const u16* Kb = Klds[j & 1];
    const u16* Vb = Vlds[j & 1];
    int kv0 = j * 64;
    bool skip = (kv0 > wrow0 + 15);
    if (!skip) {
      bool full = (kv0 + 63 <= wrow0);
      facc s[4];
#pragma unroll
      for (int nb = 0; nb < 4; ++nb) {
        s[nb] = zf;
#pragma unroll
        for (int ks = 0; ks < 8; ++ks) {
          int row = nb * 16 + l15;
          bfrag kb = *(const bfrag*)&Kb[row * 256 +
              (((ks * 64 + lg * 16) ^ ((row & 7) << 4)) >> 1)];
          s[nb] = __builtin_amdgcn_mfma_f32_16x16x32_bf16(qf[ks], kb, s[nb], 0, 0, 0);
        }
      }
      float pmax[4] = {-1e30f, -1e30f, -1e30f, -1e30f};
#pragma unroll
      for (int nb = 0; nb < 4; ++nb) {
        int col = kv0 + nb * 16 + l15;
#pragma unroll
        for (int i = 0; i < 4; ++i) {
          float vsc = s[nb][i] * 0.0625f;
          int rowa = wrow0 + lg * 4 + i;
          if (!full && col > rowa) vsc = -1e30f;
          s[nb][i] = vsc;
          pmax[i] = fmaxf(pmax[i], vsc);
        }
      }
#pragma unroll
      for (int i = 0; i < 4; ++i) {
        pmax[i] = fmaxf(pmax[i], __shfl_xor(pmax[i], 1));
        pmax[i] = fmaxf(pmax[i], __shfl_xor(pmax[i], 2));
        pmax[i] = fmaxf(pmax[i], __shfl_xor(pmax[i], 4));
        pmax[i] = fmaxf(pmax[i], __shfl_xor(pmax[i], 8));
      }
      float corr[4], rsum[4];
#pragma unroll
      for (int i = 0; i < 4; ++i) {
        float mn = fmaxf(mrow[i], pmax[i]);
        corr[i] = __expf(mrow[i] - mn);
        mrow[i] = mn;
        rsum[i] = 0.f;
      }
#pragma unroll
      for (int nb = 0; nb < 4; ++nb)
#pragma unroll
        for (int i = 0; i < 4; ++i) {
          float p = __expf(s[nb][i] - mrow[i]);
          s[nb][i] = p;
          rsum[i] += p;
        }
#pragma unroll
      for (int i = 0; i < 4; ++i) {
        rsum[i] += __shfl_xor(rsum[i], 1);
        rsum[i] += __shfl_xor(rsum[i], 2);
        rsum[i] += __shfl_xor(rsum[i], 4);
        rsum[i] += __shfl_xor(rsum[i], 8);
        lrow[i] = lrow[i] * corr[i] + rsum[i];
      }
#pragma unroll
      for (int nb = 0; nb < 16; ++nb)
#pragma unroll
        for (int i = 0; i < 4; ++i) O[nb][i] *= corr[i];
      u16* Pw = (u16*)Plds[wid];
#pragma unroll
      for (int nb = 0; nb < 4; ++nb)
#pragma unroll
        for (int i = 0; i < 4; ++i) {
          int row = lg * 4 + i;
          Pw[(row * 128 + ((nb * 32 + l15 * 2) ^ ((row & 7) << 4))) >> 1] =
              f2bf(s[nb][i]);
        }
      bfrag pa[2];
#pragma unroll
      for (int ksv = 0; ksv < 2; ++ksv)
        pa[ksv] = *(const bfrag*)&Pw[l15 * 64 +
            (((ksv * 64 + lg * 16) ^ ((l15 & 7) << 4)) >> 1)];
#pragma unroll
      for (int nb = 0; nb < 16; ++nb) {
        int d = nb * 16 + l15;
#pragma unroll
        for (int ksv = 0; ksv < 2; ++ksv) {
          bfrag vb = *(const bfrag*)&Vb[d * 64 +
              (((ksv * 64 + lg * 16) ^ ((d & 7) << 4)) >> 1)];
          O[nb] = __builtin_amdgcn_mfma_f32_16x16x32_bf16(pa[ksv], vb, O[nb], 0, 0, 0);
        }
      }
    }
  }
  float rinv[4];
#pragma unroll
  for (int i = 0; i < 4; ++i) rinv[i] = 1.f / lrow[i];
  u16* orow = ocat + (long long)(b * T_ + wrow0) * 1024 + h * 256;
#pragma unroll
  for (int nb = 0; nb < 16; ++nb)
#pragma unroll
    for (int i = 0; i < 4; ++i) {
      int row = lg * 4 + i;
      orow[(long long)row * 1024 + nb * 16 + l15] = f2bf(O[nb][i] * rinv[i]);
    }
}

// ---------------------------------------------------------------- GEMM (NT), 2-phase dbuf
// SPLITK: z selects 512-elem K-chunk of A/B and a 1M-elem out slice (2 slices).
// SWAP==2: 1D grid 8000, bijective XCD-chunked swizzle — each XCD owns ~31
// contiguous B panels (M/BM==32 fixed).
template <int BM, int BN, int LDOUT, int FLAGS, int SPLITK, int SWAP>
__global__ __launch_bounds__(256) void gemm_nt(
    const u16* __restrict__ A, int lda,
    const u16* __restrict__ B, int ldb,
    int K, void* outp, const float* __restrict__ bias) {
  constexpr int MR = BM / 32, NR = BN / 32;
  __shared__ u16 As[2][BM * 32];
  __shared__ u16 Bs[2][BN * 32];
  int gx, gy;
  if (SWAP == 2) {
    int cpx = (int)gridDim.x >> 3;
    int swz = ((int)blockIdx.x & 7) * cpx + ((int)blockIdx.x >> 3);
    gy = swz & 31;
    gx = swz >> 5;
  } else {
    gx = SWAP ? blockIdx.y : blockIdx.x;
    gy = SWAP ? blockIdx.x : blockIdx.y;
  }
  int z = blockIdx.z;
  const u16* Ab = A + (long long)gy * BM * lda + (SPLITK ? z * 512 : 0);
  const u16* Bb = B + (long long)gx * BN * ldb + (SPLITK ? z * 512 : 0);
  float* outf = (float*)outp + (SPLITK ? (long long)z * 1048576 : 0);
  u16* outh = (u16*)outp + (SPLITK ? (long long)z * 1048576 : 0);
  int tid = threadIdx.x;
  int lane = tid & 63, wid = tid >> 6;
  int wr = (wid >> 1) * (BM / 2), wc = (wid & 1) * (BN / 2);
  int srow = tid >> 2, scol = (tid & 3) * 8;

  auto stage = [&](int t, int bufi) {
    int k0 = t * 32;
#pragma unroll
    for (int i = 0; i < BM / 64; ++i)
      gload_lds16(Ab + (long long)(srow + i * 64) * lda + k0 + scol,
                  &As[bufi][(srow + i * 64) * 32 + scol]);
#pragma unroll
    for (int i = 0; i < BN / 64; ++i)
      gload_lds16(Bb + (long long)(srow + i * 64) * ldb + k0 + scol,
                  &Bs[bufi][(srow + i * 64) * 32 + scol]);
  };

  facc acc[MR][NR];
  facc zf = {0.f, 0.f, 0.f, 0.f};
#pragma unroll
  for (int m = 0; m < MR; ++m)
#pragma unroll
    for (int n = 0; n < NR; ++n) acc[m][n] = zf;

  int nt = K >> 5;
  stage(0, 0);
  __syncthreads();
  for (int t = 0; t < nt; ++t) {
    int cur = t & 1;
    if (t + 1 < nt) stage(t + 1, cur ^ 1);
    int kk = (lane >> 4) * 8;
    int ar = wr + (lane & 15);
    int br = wc + (lane & 15);
    bfrag af[MR], bfv[NR];
#pragma unroll
    for (int m = 0; m < MR; ++m) af[m] = *(const bfrag*)&As[cur][(ar + m * 16) * 32 + kk];
#pragma unroll
    for (int n = 0; n < NR; ++n) bfv[n] = *(const bfrag*)&Bs[cur][(br + n * 16) * 32 + kk];
#pragma unroll
    for (int m = 0; m < MR; ++m)
#pragma unroll
      for (int n = 0; n < NR; ++n)
        acc[m][n] = __builtin_amdgcn_mfma_f32_16x16x32_bf16(af[m], bfv[n], acc[m][n], 0, 0, 0);
    __syncthreads();
  }

  int rg = (lane >> 4) * 4;
  int cl = lane & 15;
  int rbase = gy * BM + wr + rg;
  int cbase = gx * BN + wc + cl;
#pragma unroll
  for (int m = 0; m < MR; ++m) {
#pragma unroll
    for (int n = 0; n < NR; ++n) {
      int c_abs = cbase + n * 16;
      float bvv = (FLAGS & FLAG_BIAS) ? bias[c_abs] : 0.f;
#pragma unroll
      for (int i = 0; i < 4; ++i) {
        int r = rbase + m * 16 + i;
        float val = acc[m][n][i] + bvv;
        if (FLAGS & FLAG_RELU) val = fmaxf(val, 0.f);
        int oi = r * LDOUT + c_abs;       // int32, LDOUT compile-time
        if (FLAGS & FLAG_BF16) outh[oi] = f2bf(val);
        else if (FLAGS & FLAG_NT) __builtin_nontemporal_store(val, &outf[oi]);
        else outf[oi] = val;
      }
    }
  }
}

// ---------------------------------------------------------------- launch
extern "C" void kernel_launch(void* const* d_in, const int* in_sizes, int n_in,
                              void* d_out, int out_size, void* d_ws, size_t ws_size,
                              hipStream_t stream) {
  (void)in_sizes; (void)n_in; (void)out_size; (void)ws_size;
  const int*   tokens = (const int*)d_in[0];
  const float* embed  = (const float*)d_in[1];
  const float* pos    = (const float*)d_in[2];
  const float* ln1_g  = (const float*)d_in[3];
  const float* ln1_b  = (const float*)d_in[4];
  const float* wq     = (const float*)d_in[5];
  const float* wk     = (const float*)d_in[6];
  const float* wv     = (const float*)d_in[7];
  const float* wo     = (const float*)d_in[8];
  const float* wo_b   = (const float*)d_in[9];
  const float* ln2_g  = (const float*)d_in[10];
  const float* ln2_b  = (const float*)d_in[11];
  const float* w1     = (const float*)d_in[12];
  const float* b1     = (const float*)d_in[13];
  const float* w2     = (const float*)d_in[14];
  const float* b2     = (const float*)d_in[15];
  const float* lnf_g  = (const float*)d_in[16];
  const float* lnf_b  = (const float*)d_in[17];
  const float* wf     = (const float*)d_in[18];
  const float* bf     = (const float*)d_in[19];
  float* out = (float*)d_out;

  char* ws = (char*)d_ws;
  size_t off = 0;
  auto alloc = [&](size_t bytes) -> char* {
    char* p = ws + off;
    off += (bytes + 255) & ~(size_t)255;
    return p;
  };
  const long long NR = (long long)B_ * T_;
  u16* xn    = (u16*)alloc(NR * C_ * 2);           // single bf16 residual stream
  u16* qkv   = (u16*)alloc(NR * 3072LL * 2);
  u16* vt    = (u16*)alloc((long long)B_ * H_ * C_ * T_ * 2);
  u16* ocat  = (u16*)alloc(NR * (long long)(H_ * C_) * 2);
  u16* hdn   = (u16*)alloc(NR * (long long)FF * 2);
  u16* pbuf  = (u16*)alloc(2LL * NR * C_ * 2);     // split-K(2) partials bf16
  u16* wqkvT = (u16*)alloc((long long)L_ * 3 * H_ * C_ * C_ * 2);
  u16* woT   = (u16*)alloc((long long)L_ * C_ * (H_ * C_) * 2);
  u16* w1T   = (u16*)alloc((long long)L_ * FF * C_ * 2);
  u16* w2T   = (u16*)alloc((long long)L_ * C_ * FF * 2);
  u16* wfT   = (u16*)alloc((long long)V_ * C_ * 2);

  dim3 tb(256);

  transpose_all<<<dim3(14144), tb, 0, stream>>>(wq, wk, wv, wo, w1, w2, wf,
                                                wqkvT, woT, w1T, w2T, wfT);
  embed_ln<<<dim3(1024), tb, 0, stream>>>(tokens, embed, pos, xn, ln1_g, ln1_b);

  for (int l = 0; l < L_; ++l) {
    // QKV: [4096,256]@[3072,256]^T -> qkv [4096][3072]; 128x128 tile, 768 blocks (~3/CU)
    gemm_nt<128, 128, 3072, FLAG_BF16, 0, 0><<<dim3(24, 32, 1), tb, 0, stream>>>(
        xn, C_, wqkvT + (long long)l * 3 * 1024 * 256, C_, C_, qkv, nullptr);
    transpose_v<<<dim3(64, 8, 8), tb, 0, stream>>>(qkv, vt);
    flash_k<<<dim3(256), tb, 0, stream>>>(qkv, vt, ocat);
    // WO: split-K x2 (K=512/slice) -> pbuf bf16
    gemm_nt<64, 64, 256, FLAG_BF16, 1, 0><<<dim3(4, 64, 2), tb, 0, stream>>>(
        ocat, H_ * C_, woT + (long long)l * C_ * H_ * C_, H_ * C_, 512, pbuf, nullptr);
    reduce_ln<<<dim3(1024), tb, 0, stream>>>(pbuf, xn, wo_b + l * C_,
                                             ln2_g + l * C_, ln2_b + l * C_);
    // MLP1
    gemm_nt<64, 64, 1024, FLAG_BIAS | FLAG_RELU | FLAG_BF16, 0, 0>
        <<<dim3(16, 64, 1), tb, 0, stream>>>(
        xn, C_, w1T + (long long)l * FF * C_, C_, C_, hdn, b1 + l * FF);
    // MLP2: split-K x2 (K=512/slice) -> pbuf bf16
    gemm_nt<64, 64, 256, FLAG_BF16, 1, 0><<<dim3(4, 64, 2), tb, 0, stream>>>(
        hdn, FF, w2T + (long long)l * C_ * FF, FF, 512, pbuf, nullptr);
    const float* ng = (l < 3) ? (ln1_g + (l + 1) * C_) : lnf_g;
    const float* nb = (l < 3) ? (ln1_b + (l + 1) * C_) : lnf_b;
    reduce_ln<<<dim3(1024), tb, 0, stream>>>(pbuf, xn, b2 + l * C_, ng, nb);
  }
  // logits = xn @ wf + bf  (fp32, nontemporal); 1D grid + XCD-chunked swizzle
  gemm_nt<128, 128, 32000, FLAG_BIAS | FLAG_NT, 0, 2><<<dim3(8000, 1, 1), tb, 0, stream>>>(
      xn, C_, wfT, C_, C_, out, bf);
}